// Round 7
// baseline (311.238 us; speedup 1.0000x reference)
//
#include <hip/hip_runtime.h>
#include <stdint.h>
#include <math.h>

typedef _Float16 half8_t __attribute__((ext_vector_type(8)));
typedef float floatx4 __attribute__((ext_vector_type(4)));

#define NN 20000
#define NE 40000
#define NG 1000
#define NBLK 313      // ceil(NE/128)  -- 128 edges per block
#define NSPLIT 4

// ---- fused prep: [0,1250) x0->e16 pad ; [1250,1680) w2 -> B-frag images ; [1680..) deg=0 ----
// Chunk counts (NSPLIT=4): L0 = 68 (4x17), L1 = 132 (4x33), L2 = 264 (4x66).
__global__ __launch_bounds__(256) void prep_fused_kernel(
    const float* __restrict__ x, _Float16* __restrict__ e16,
    const float* __restrict__ w2a, const float* __restrict__ b2a, _Float16* __restrict__ oa,
    const float* __restrict__ w2b, const float* __restrict__ b2b, _Float16* __restrict__ ob,
    const float* __restrict__ w2c, const float* __restrict__ b2c, _Float16* __restrict__ oc,
    int* __restrict__ deg)
{
  if (blockIdx.x < 1250) {
    int idx = blockIdx.x * 256 + threadIdx.x;   // over NN*16
    int n = idx >> 4, i = idx & 15;
    e16[idx] = (i < 13) ? (_Float16)x[(size_t)n * 13 + i] : (_Float16)0.f;
    return;
  }
  if (blockIdx.x >= 1680) {
    int n = (blockIdx.x - 1680) * 256 + threadIdx.x;
    if (n < NN) deg[n] = 0;
    return;
  }
  const int TOT0 = 68 * 2 * 64, TOT1 = 132 * 4 * 64, TOT2 = 264 * 4 * 64;
  int idx = (blockIdx.x - 1250) * 256 + threadIdx.x;
  const float *w2, *b2; _Float16* op; int mi, mo, mpsh, CT;
  if (idx < TOT0) { w2 = w2a; b2 = b2a; op = oa; mi = 13; mo = 32; mpsh = 4; CT = 2; }
  else if (idx < TOT0 + TOT1) { idx -= TOT0; w2 = w2b; b2 = b2b; op = ob; mi = 32; mo = 64; mpsh = 5; CT = 4; }
  else if (idx < TOT0 + TOT1 + TOT2) { idx -= TOT0 + TOT1; w2 = w2c; b2 = b2c; op = oc; mi = 64; mo = 64; mpsh = 6; CT = 4; }
  else return;
  int l = idx & 63;
  int ct = (idx >> 6) % CT;
  int c = idx / (64 * CT);
  int q = l >> 4;
  int n = ct * 16 + (l & 15);
  int mask = (1 << mpsh) - 1;
  half8_t v;
#pragma unroll
  for (int j = 0; j < 8; ++j) {
    int r = c * 32 + q * 8 + j;
    int k = r >> mpsh, i = r & mask;
    float f = 0.f;
    if (i < mi) {
      if (k < 128) f = w2[(size_t)(k * mi + i) * mo + n];
      else if (k == 128) f = b2[(size_t)i * mo + n];
    }
    v[j] = (_Float16)f;
  }
  *(half8_t*)(op + (size_t)idx * 8) = v;
}

// ---- CSR build: histogram, parallel scan, fill ----
__global__ __launch_bounds__(256) void deg_kernel(const int* __restrict__ dst, int* __restrict__ deg) {
  int e = blockIdx.x * 256 + threadIdx.x;
  if (e < NE) atomicAdd(&deg[dst[e]], 1);
}

__global__ __launch_bounds__(1024) void scan_kernel(
    const int* __restrict__ deg, int* __restrict__ row_ptr, int* __restrict__ cursor)
{
  constexpr int CH = 20;                 // 1024*20 = 20480 >= NN+1
  __shared__ int wsum[16];
  int t = threadIdx.x;
  int lane = t & 63, w = t >> 6;
  int base = t * CH;
  int local[CH];
#pragma unroll
  for (int i = 0; i < CH; ++i) {
    int n = base + i;
    local[i] = (n < NN) ? deg[n] : 0;
  }
  int s = 0;
#pragma unroll
  for (int i = 0; i < CH; ++i) s += local[i];
  int sc = s;
#pragma unroll
  for (int d = 1; d < 64; d <<= 1) {
    int v = __shfl_up(sc, d, 64);
    if (lane >= d) sc += v;
  }
  if (lane == 63) wsum[w] = sc;
  __syncthreads();
  if (w == 0 && lane < 16) {
    int v = wsum[lane];
    int scc = v;
#pragma unroll
    for (int d = 1; d < 16; d <<= 1) {
      int u = __shfl_up(scc, d, 64);
      if (lane >= d) scc += u;
    }
    wsum[lane] = scc - v;                // exclusive wave prefix
  }
  __syncthreads();
  int run = wsum[w] + (sc - s);          // exclusive prefix for this thread
#pragma unroll
  for (int i = 0; i < CH; ++i) {
    int n = base + i;
    if (n < NN) { row_ptr[n] = run; cursor[n] = run; run += local[i]; }
    else if (n == NN) row_ptr[NN] = run;
  }
}

__global__ __launch_bounds__(256) void fill_kernel(
    const int* __restrict__ dst, int* __restrict__ cursor, int* __restrict__ eids)
{
  int e = blockIdx.x * 256 + threadIdx.x;
  if (e < NE) { int p = atomicAdd(&cursor[dst[e]], 1); eids[p] = e; }
}

// ---------------- fused h-MLP + message GEMM, partial-store epilogue (NO atomics) ----------------
// LDS-pipe diet: W B-fragments read DIRECTLY from global (L2-resident, L1-served across waves;
// no LDS staging, no ds_write, no K-loop barriers). LDS holds only h16 + w1s.
// K-loop per chunk per wave: 4 global b128 loads + 2 broadcast h reads + 8 MFMA.
template <int MIP, int MO, int NCC, int KCNT>
__global__ __launch_bounds__(256, 4) void msg9_kernel(
    const float* __restrict__ ea, const float* __restrict__ w1,
    const float* __restrict__ b1, const _Float16* __restrict__ xe,
    const int* __restrict__ src,
    const _Float16* __restrict__ w2h, _Float16* __restrict__ msgp)
{
  constexpr int EPB = 128;                // edges per block
  constexpr int CT = MO / 16;
  constexpr int CHB = CT * 1024;          // BYTES per K32-chunk of W image
  constexpr int XV = (MIP == 64) ? 2 : 1;
  constexpr int KH = (KCNT + 1) >> 1;     // h k-values per thread-half

  __shared__ _Float16 h16[KCNT * EPB];    // transposed: h16[kl][edge]
  __shared__ float w1s[5 * 128 + 128];

  const int t = threadIdx.x;
  const int wave = t >> 6, lane = t & 63;
  const int l15 = lane & 15, q = lane >> 4;
  const int split = blockIdx.x / NBLK;
  const int e0 = (blockIdx.x % NBLK) * EPB;
  const int c0 = NCC * split;
  const int kg0 = KCNT * split;

  const char* wgp = (const char*)w2h + (size_t)c0 * CHB;

  // ---- x fragments direct from global (2 M-subtiles per wave) ----
  const int wbase = wave * 32;
  half8_t xf[2][XV];
#pragma unroll
  for (int s = 0; s < 2; ++s) {
    int eg = e0 + wbase + s * 16 + l15; if (eg >= NE) eg = NE - 1;
    const _Float16* xr = xe + (size_t)src[eg] * MIP;
    int i0 = (MIP == 16) ? (q & 1) * 8 : q * 8;
    xf[s][0] = *(const half8_t*)(xr + i0);
    if constexpr (MIP == 64)
      xf[s][XV - 1] = *(const half8_t*)(xr + 32 + q * 8);
  }

  // ---- edge attrs to regs (thread-half te owns edge e0+te); w1/b1 to LDS ----
  const int te = t & 127;
  float ear[5];
  {
    int eg = e0 + te; if (eg >= NE) eg = NE - 1;
#pragma unroll
    for (int j = 0; j < 5; ++j) ear[j] = ea[(size_t)eg * 5 + j];
  }
  for (int i = t; i < 768; i += 256) w1s[i] = (i < 640) ? w1[i] : b1[i - 640];
  __syncthreads();

  // ---- h phase: each edge's KCNT values split across thread halves ----
  {
    int kh = t >> 7;
    int klo = kh * KH;
    int khi = klo + KH; if (khi > KCNT) khi = KCNT;
    for (int kl = klo; kl < khi; ++kl) {
      int kg = kg0 + kl;
      float v;
      if (kg < 128) {
        v = w1s[640 + kg];
#pragma unroll
        for (int j = 0; j < 5; ++j) v = fmaf(ear[j], w1s[j * 128 + kg], v);
        v = fmaxf(v, 0.f);
      } else v = (kg == 128) ? 1.f : 0.f;
      h16[kl * EPB + te] = (_Float16)v;
    }
  }
  __syncthreads();

  // ---- K loop: barrier-free; B-fragments streamed from global (L1/L2-served) ----
  floatx4 acc[2][CT];
#pragma unroll
  for (int s = 0; s < 2; ++s)
#pragma unroll
    for (int b = 0; b < CT; ++b) acc[s][b] = (floatx4){0.f, 0.f, 0.f, 0.f};

#pragma unroll 4
  for (int cc = 0; cc < NCC; ++cc) {
    half8_t bf[CT];
#pragma unroll
    for (int b = 0; b < CT; ++b)
      bf[b] = *(const half8_t*)(wgp + (size_t)cc * CHB + (b * 64 + lane) * 16);
    int kl;
    if constexpr (MIP == 64) kl = cc >> 1;
    else if constexpr (MIP == 32) kl = cc;
    else kl = 2 * cc + (q >> 1);
#pragma unroll
    for (int s = 0; s < 2; ++s) {
      _Float16 hv = h16[kl * EPB + wbase + s * 16 + l15];
      half8_t af;
      if constexpr (MIP == 64) af = xf[s][cc & 1] * hv;
      else af = xf[s][0] * hv;
#pragma unroll
      for (int b = 0; b < CT; ++b)
        acc[s][b] = __builtin_amdgcn_mfma_f32_16x16x32_f16(af, bf[b], acc[s][b], 0, 0, 0);
    }
  }

  // ---- epilogue: plain fp16 partial stores, no atomics ----
  _Float16* mp = msgp + (size_t)split * NE * MO;
#pragma unroll
  for (int s = 0; s < 2; ++s) {
    int rowb = wbase + s * 16 + q * 4;
#pragma unroll
    for (int b = 0; b < CT; ++b) {
      int n = b * 16 + l15;
#pragma unroll
      for (int r = 0; r < 4; ++r) {
        int row = rowb + r;
        int e = e0 + row;
        if (e < NE) mp[(size_t)e * MO + n] = (_Float16)acc[s][b][r];
      }
    }
  }
}

// ---- gather: per node, sum CSR-listed edge partials (+root-GEMM +bias), ELU unless FINAL ----
template <int MIN_, int XST, int MO, int FINAL>
__global__ __launch_bounds__(256) void gather_kernel(
    const _Float16* __restrict__ e16in, const float* __restrict__ root,
    const float* __restrict__ bias, const int* __restrict__ row_ptr,
    const int* __restrict__ eids, const _Float16* __restrict__ msgp,
    _Float16* __restrict__ oute, float* __restrict__ outf)
{
  constexpr int NPB = 256 / MO;
  int n = blockIdx.x * NPB + threadIdx.x / MO;
  int o = threadIdx.x % MO;
  if (n >= NN) return;
  float a = bias[o];
#pragma unroll
  for (int i = 0; i < MIN_; ++i)
    a = fmaf((float)e16in[(size_t)n * XST + i], root[i * MO + o], a);
  int r0 = row_ptr[n], r1 = row_ptr[n + 1];
  for (int j = r0; j < r1; ++j) {
    int e = eids[j];
#pragma unroll
    for (int s = 0; s < NSPLIT; ++s)
      a += (float)msgp[((size_t)s * NE + e) * MO + o];
  }
  if constexpr (FINAL) {
    outf[(size_t)n * MO + o] = a;
  } else {
    float v = a > 0.f ? a : (expf(a) - 1.f);
    oute[(size_t)n * MO + o] = (_Float16)v;
  }
}

// ---- pooling (segment mean over sorted batch, fused ELU) + 3-layer FC head ----
__global__ __launch_bounds__(64) void pool_fc_kernel(
    const float* __restrict__ xn2, const int* __restrict__ batch,
    const float* __restrict__ f1w, const float* __restrict__ f1b,
    const float* __restrict__ f2w, const float* __restrict__ f2b,
    const float* __restrict__ f3w, const float* __restrict__ f3b,
    float* __restrict__ out)
{
  __shared__ float xg[64]; __shared__ float a1[32]; __shared__ float a2[16];
  int g = blockIdx.x, t = threadIdx.x;
  int lo = 0, hi = NN;
  while (lo < hi) { int m = (lo + hi) >> 1; if (batch[m] < g) lo = m + 1; else hi = m; }
  int start = lo; hi = NN;
  while (lo < hi) { int m = (lo + hi) >> 1; if (batch[m] <= g) lo = m + 1; else hi = m; }
  int end = lo;
  float acc = 0.f;
  for (int n = start; n < end; ++n) {
    float v = xn2[(size_t)n * 64 + t];
    acc += v > 0.f ? v : (expf(v) - 1.f);
  }
  float c = (end > start) ? (float)(end - start) : 1.f;
  xg[t] = acc / c;
  __syncthreads();
  if (t < 32) {
    float a = f1b[t];
    for (int i = 0; i < 64; ++i) a = fmaf(xg[i], f1w[i * 32 + t], a);
    a1[t] = a > 0.f ? a : (expf(a) - 1.f);
  }
  __syncthreads();
  if (t < 16) {
    float a = f2b[t];
    for (int i = 0; i < 32; ++i) a = fmaf(a1[i], f2w[i * 16 + t], a);
    a2[t] = a > 0.f ? a : (expf(a) - 1.f);
  }
  __syncthreads();
  if (t == 0) {
    float a = f3b[0];
    for (int i = 0; i < 16; ++i) a = fmaf(a2[i], f3w[i], a);
    out[g] = a;
  }
}

extern "C" void kernel_launch(void* const* d_in, const int* in_sizes, int n_in,
                              void* d_out, int out_size, void* d_ws, size_t ws_size,
                              hipStream_t stream)
{
  const float* x_in  = (const float*)d_in[0];
  const int*   ei    = (const int*)d_in[1];
  const float* ea    = (const float*)d_in[2];
  const int*   batch = (const int*)d_in[3];
  const float* W1[3] = {(const float*)d_in[4],  (const float*)d_in[10], (const float*)d_in[16]};
  const float* B1[3] = {(const float*)d_in[5],  (const float*)d_in[11], (const float*)d_in[17]};
  const float* W2[3] = {(const float*)d_in[6],  (const float*)d_in[12], (const float*)d_in[18]};
  const float* B2[3] = {(const float*)d_in[7],  (const float*)d_in[13], (const float*)d_in[19]};
  const float* RT[3] = {(const float*)d_in[8],  (const float*)d_in[14], (const float*)d_in[20]};
  const float* BS[3] = {(const float*)d_in[9],  (const float*)d_in[15], (const float*)d_in[21]};
  const float* f1w = (const float*)d_in[22]; const float* f1b = (const float*)d_in[23];
  const float* f2w = (const float*)d_in[24]; const float* f2b = (const float*)d_in[25];
  const float* f3w = (const float*)d_in[26]; const float* f3b = (const float*)d_in[27];

  char* ws = (char*)d_ws;
  size_t off = 0;
  auto alloc = [&](size_t bytes) { void* p = ws + off; off += (bytes + 255) & ~(size_t)255; return p; };
  float*    xn2   = (float*)alloc((size_t)NN * 64 * 4);
  _Float16* e16_0 = (_Float16*)alloc((size_t)NN * 16 * 2);
  _Float16* e16_1 = (_Float16*)alloc((size_t)NN * 32 * 2);
  _Float16* e16_2 = (_Float16*)alloc((size_t)NN * 64 * 2);
  _Float16* w2h0  = (_Float16*)alloc((size_t)68 * 2048);
  _Float16* w2h1  = (_Float16*)alloc((size_t)132 * 4096);
  _Float16* w2h2  = (_Float16*)alloc((size_t)264 * 4096);
  _Float16* msgp  = (_Float16*)alloc((size_t)NSPLIT * NE * 64 * 2);
  int*      deg     = (int*)alloc((size_t)NN * 4);
  int*      row_ptr = (int*)alloc((size_t)(NN + 1) * 4);
  int*      cursor  = (int*)alloc((size_t)NN * 4);
  int*      eids    = (int*)alloc((size_t)NE * 4);

  const int* srcp = ei;
  const int* dstp = ei + NE;

  prep_fused_kernel<<<1680 + (NN + 255) / 256, 256, 0, stream>>>(
      x_in, e16_0, W2[0], B2[0], w2h0, W2[1], B2[1], w2h1, W2[2], B2[2], w2h2, deg);
  deg_kernel<<<(NE + 255) / 256, 256, 0, stream>>>(dstp, deg);
  scan_kernel<<<1, 1024, 0, stream>>>(deg, row_ptr, cursor);
  fill_kernel<<<(NE + 255) / 256, 256, 0, stream>>>(dstp, cursor, eids);

  // ---- layer 0: 17 chunks/split, KCNT=34 ----
  msg9_kernel<16, 32, 17, 34><<<NBLK * NSPLIT, 256, 0, stream>>>(
      ea, W1[0], B1[0], e16_0, srcp, w2h0, msgp);
  gather_kernel<13, 16, 32, 0><<<(NN + 7) / 8, 256, 0, stream>>>(
      e16_0, RT[0], BS[0], row_ptr, eids, msgp, e16_1, xn2);

  // ---- layer 1: 33 chunks/split, KCNT=33 ----
  msg9_kernel<32, 64, 33, 33><<<NBLK * NSPLIT, 256, 0, stream>>>(
      ea, W1[1], B1[1], e16_1, srcp, w2h1, msgp);
  gather_kernel<32, 32, 64, 0><<<(NN + 3) / 4, 256, 0, stream>>>(
      e16_1, RT[1], BS[1], row_ptr, eids, msgp, e16_2, xn2);

  // ---- layer 2: 66 chunks/split, KCNT=33 ----
  msg9_kernel<64, 64, 66, 33><<<NBLK * NSPLIT, 256, 0, stream>>>(
      ea, W1[2], B1[2], e16_2, srcp, w2h2, msgp);
  gather_kernel<64, 64, 64, 1><<<(NN + 3) / 4, 256, 0, stream>>>(
      e16_2, RT[2], BS[2], row_ptr, eids, msgp, e16_2, xn2);

  pool_fc_kernel<<<NG, 64, 0, stream>>>(xn2, batch, f1w, f1b, f2w, f2b, f3w, f3b, (float*)d_out);
}

// Round 8
// 306.855 us; speedup vs baseline: 1.0143x; 1.0143x over previous
//
#include <hip/hip_runtime.h>
#include <stdint.h>
#include <math.h>

typedef _Float16 half8_t __attribute__((ext_vector_type(8)));
typedef float floatx4 __attribute__((ext_vector_type(4)));

#define NN 20000
#define NE 40000
#define NG 1000
#define NBLK 313      // ceil(NE/128)  -- 128 edges per block
#define NSPLIT 4

// ---- fused prep: [0,1250) x0->e16 pad ; [1250,1680) w2 -> B-frag images ; [1680..) deg=0 ----
// Chunk counts (NSPLIT=4): L0 = 68 (4x17), L1 = 132 (4x33), L2 = 264 (4x66).
__global__ __launch_bounds__(256) void prep_fused_kernel(
    const float* __restrict__ x, _Float16* __restrict__ e16,
    const float* __restrict__ w2a, const float* __restrict__ b2a, _Float16* __restrict__ oa,
    const float* __restrict__ w2b, const float* __restrict__ b2b, _Float16* __restrict__ ob,
    const float* __restrict__ w2c, const float* __restrict__ b2c, _Float16* __restrict__ oc,
    int* __restrict__ deg)
{
  if (blockIdx.x < 1250) {
    int idx = blockIdx.x * 256 + threadIdx.x;   // over NN*16
    int n = idx >> 4, i = idx & 15;
    e16[idx] = (i < 13) ? (_Float16)x[(size_t)n * 13 + i] : (_Float16)0.f;
    return;
  }
  if (blockIdx.x >= 1680) {
    int n = (blockIdx.x - 1680) * 256 + threadIdx.x;
    if (n < NN) deg[n] = 0;
    return;
  }
  const int TOT0 = 68 * 2 * 64, TOT1 = 132 * 4 * 64, TOT2 = 264 * 4 * 64;
  int idx = (blockIdx.x - 1250) * 256 + threadIdx.x;
  const float *w2, *b2; _Float16* op; int mi, mo, mpsh, CT;
  if (idx < TOT0) { w2 = w2a; b2 = b2a; op = oa; mi = 13; mo = 32; mpsh = 4; CT = 2; }
  else if (idx < TOT0 + TOT1) { idx -= TOT0; w2 = w2b; b2 = b2b; op = ob; mi = 32; mo = 64; mpsh = 5; CT = 4; }
  else if (idx < TOT0 + TOT1 + TOT2) { idx -= TOT0 + TOT1; w2 = w2c; b2 = b2c; op = oc; mi = 64; mo = 64; mpsh = 6; CT = 4; }
  else return;
  int l = idx & 63;
  int ct = (idx >> 6) % CT;
  int c = idx / (64 * CT);
  int q = l >> 4;
  int n = ct * 16 + (l & 15);
  int mask = (1 << mpsh) - 1;
  half8_t v;
#pragma unroll
  for (int j = 0; j < 8; ++j) {
    int r = c * 32 + q * 8 + j;
    int k = r >> mpsh, i = r & mask;
    float f = 0.f;
    if (i < mi) {
      if (k < 128) f = w2[(size_t)(k * mi + i) * mo + n];
      else if (k == 128) f = b2[(size_t)i * mo + n];
    }
    v[j] = (_Float16)f;
  }
  *(half8_t*)(op + (size_t)idx * 8) = v;
}

// ---- CSR build: histogram, parallel scan, fill ----
__global__ __launch_bounds__(256) void deg_kernel(const int* __restrict__ dst, int* __restrict__ deg) {
  int e = blockIdx.x * 256 + threadIdx.x;
  if (e < NE) atomicAdd(&deg[dst[e]], 1);
}

__global__ __launch_bounds__(1024) void scan_kernel(
    const int* __restrict__ deg, int* __restrict__ row_ptr, int* __restrict__ cursor)
{
  constexpr int CH = 20;                 // 1024*20 = 20480 >= NN+1
  __shared__ int wsum[16];
  int t = threadIdx.x;
  int lane = t & 63, w = t >> 6;
  int base = t * CH;
  int local[CH];
#pragma unroll
  for (int i = 0; i < CH; ++i) {
    int n = base + i;
    local[i] = (n < NN) ? deg[n] : 0;
  }
  int s = 0;
#pragma unroll
  for (int i = 0; i < CH; ++i) s += local[i];
  int sc = s;
#pragma unroll
  for (int d = 1; d < 64; d <<= 1) {
    int v = __shfl_up(sc, d, 64);
    if (lane >= d) sc += v;
  }
  if (lane == 63) wsum[w] = sc;
  __syncthreads();
  if (w == 0 && lane < 16) {
    int v = wsum[lane];
    int scc = v;
#pragma unroll
    for (int d = 1; d < 16; d <<= 1) {
      int u = __shfl_up(scc, d, 64);
      if (lane >= d) scc += u;
    }
    wsum[lane] = scc - v;                // exclusive wave prefix
  }
  __syncthreads();
  int run = wsum[w] + (sc - s);          // exclusive prefix for this thread
#pragma unroll
  for (int i = 0; i < CH; ++i) {
    int n = base + i;
    if (n < NN) { row_ptr[n] = run; cursor[n] = run; run += local[i]; }
    else if (n == NN) row_ptr[NN] = run;
  }
}

__global__ __launch_bounds__(256) void fill_kernel(
    const int* __restrict__ dst, int* __restrict__ cursor, int* __restrict__ eids)
{
  int e = blockIdx.x * 256 + threadIdx.x;
  if (e < NE) { int p = atomicAdd(&cursor[dst[e]], 1); eids[p] = e; }
}

// ---------------- L0 message kernel: R6 structure (proven), LDS W staging ----------------
template <int MIP, int MO, int NCC, int KCNT>
__global__ __launch_bounds__(256, 4) void msg9_kernel(
    const float* __restrict__ ea, const float* __restrict__ w1,
    const float* __restrict__ b1, const _Float16* __restrict__ xe,
    const int* __restrict__ src,
    const _Float16* __restrict__ w2h, _Float16* __restrict__ msgp)
{
  constexpr int EPB = 128;                // edges per block
  constexpr int CT = MO / 16;
  constexpr int CHB = CT * 1024;          // BYTES per K32-chunk of W image
  constexpr int XV = (MIP == 64) ? 2 : 1;
  constexpr int KH = (KCNT + 1) >> 1;     // h k-values per thread-half

  __shared__ uint4 wsb[2][CHB / 16];
  __shared__ _Float16 h16[KCNT * EPB];    // transposed: h16[kl][edge]
  __shared__ float w1s[5 * 128 + 128];

  const int t = threadIdx.x;
  const int wave = t >> 6, lane = t & 63;
  const int l15 = lane & 15, q = lane >> 4;
  const int split = blockIdx.x / NBLK;
  const int e0 = (blockIdx.x % NBLK) * EPB;
  const int c0 = NCC * split;
  const int kg0 = KCNT * split;

  // ---- W prefetch: first two chunks into named registers ----
  const char* wgp = (const char*)w2h + (size_t)c0 * CHB;
  uint4 ra4, rb4; uint2 ra2, rb2;
  if constexpr (CT == 4) {
    ra4 = *(const uint4*)(wgp + t * 16);
    rb4 = *(const uint4*)(wgp + CHB + t * 16);
  } else {
    ra2 = *(const uint2*)(wgp + t * 8);
    rb2 = *(const uint2*)(wgp + CHB + t * 8);
  }

  // ---- x fragments direct from global (2 M-subtiles per wave) ----
  const int wbase = wave * 32;
  half8_t xf[2][XV];
#pragma unroll
  for (int s = 0; s < 2; ++s) {
    int eg = e0 + wbase + s * 16 + l15; if (eg >= NE) eg = NE - 1;
    const _Float16* xr = xe + (size_t)src[eg] * MIP;
    int i0 = (MIP == 16) ? (q & 1) * 8 : q * 8;
    xf[s][0] = *(const half8_t*)(xr + i0);
    if constexpr (MIP == 64)
      xf[s][XV - 1] = *(const half8_t*)(xr + 32 + q * 8);
  }

  // ---- edge attrs to regs (thread-half te owns edge e0+te); w1/b1 to LDS ----
  const int te = t & 127;
  float ear[5];
  {
    int eg = e0 + te; if (eg >= NE) eg = NE - 1;
#pragma unroll
    for (int j = 0; j < 5; ++j) ear[j] = ea[(size_t)eg * 5 + j];
  }
  for (int i = t; i < 768; i += 256) w1s[i] = (i < 640) ? w1[i] : b1[i - 640];
  __syncthreads();

  // ---- h phase: each edge's KCNT values split across thread halves ----
  {
    int kh = t >> 7;
    int klo = kh * KH;
    int khi = klo + KH; if (khi > KCNT) khi = KCNT;
    for (int kl = klo; kl < khi; ++kl) {
      int kg = kg0 + kl;
      float v;
      if (kg < 128) {
        v = w1s[640 + kg];
#pragma unroll
        for (int j = 0; j < 5; ++j) v = fmaf(ear[j], w1s[j * 128 + kg], v);
        v = fmaxf(v, 0.f);
      } else v = (kg == 128) ? 1.f : 0.f;
      h16[kl * EPB + te] = (_Float16)v;
    }
  }
  __syncthreads();

  // ---- K loop: 1 barrier/chunk, LDS double-buffer, 2-deep register prefetch ----
  floatx4 acc[2][CT];
#pragma unroll
  for (int s = 0; s < 2; ++s)
#pragma unroll
    for (int b = 0; b < CT; ++b) acc[s][b] = (floatx4){0.f, 0.f, 0.f, 0.f};

#pragma unroll 2
  for (int cc = 0; cc < NCC; ++cc) {
    const bool odd = (cc & 1) != 0;
    if constexpr (CT == 4) wsb[cc & 1][t] = odd ? rb4 : ra4;
    else ((uint2*)wsb[cc & 1])[t] = odd ? rb2 : ra2;
    if (cc + 2 < NCC) {
      const char* np = wgp + (size_t)(cc + 2) * CHB;
      if constexpr (CT == 4) {
        if (odd) rb4 = *(const uint4*)(np + t * 16); else ra4 = *(const uint4*)(np + t * 16);
      } else {
        if (odd) rb2 = *(const uint2*)(np + t * 8); else ra2 = *(const uint2*)(np + t * 8);
      }
    }
    __syncthreads();
    const _Float16* wb = (const _Float16*)wsb[cc & 1];
    half8_t bf[CT];
#pragma unroll
    for (int b = 0; b < CT; ++b)
      bf[b] = *(const half8_t*)(wb + (b * 64 + lane) * 8);
    int kl;
    if constexpr (MIP == 64) kl = cc >> 1;
    else if constexpr (MIP == 32) kl = cc;
    else kl = 2 * cc + (q >> 1);
#pragma unroll
    for (int s = 0; s < 2; ++s) {
      _Float16 hv = h16[kl * EPB + wbase + s * 16 + l15];
      half8_t af;
      if constexpr (MIP == 64) af = xf[s][cc & 1] * hv;
      else af = xf[s][0] * hv;
#pragma unroll
      for (int b = 0; b < CT; ++b)
        acc[s][b] = __builtin_amdgcn_mfma_f32_16x16x32_f16(af, bf[b], acc[s][b], 0, 0, 0);
    }
  }

  // ---- epilogue: plain fp16 partial stores, no atomics ----
  _Float16* mp = msgp + (size_t)split * NE * MO;
#pragma unroll
  for (int s = 0; s < 2; ++s) {
    int rowb = wbase + s * 16 + q * 4;
#pragma unroll
    for (int b = 0; b < CT; ++b) {
      int n = b * 16 + l15;
#pragma unroll
      for (int r = 0; r < 4; ++r) {
        int row = rowb + r;
        int e = e0 + row;
        if (e < NE) mp[(size_t)e * MO + n] = (_Float16)acc[s][b][r];
      }
    }
  }
}

// ---------------- L1/L2 message kernel: N-split waves, direct-global W, barrier-free K-loop ----
// Each wave owns one 16-col N-tile (MO=64, CT=4) and ALL 128 rows (8 M-subtiles).
// Per chunk per wave: 1 global b128 (disjoint W slice) + 8 MFMA. No ds_write, no K barriers.
// h in LDS as [kl-group][edge][8], read via ds_read_b128 once per 8 kl per subtile.
template <int MIP, int NCC, int KCNT>
__global__ __launch_bounds__(256, 3) void msgN_kernel(
    const float* __restrict__ ea, const float* __restrict__ w1,
    const float* __restrict__ b1, const _Float16* __restrict__ xe,
    const int* __restrict__ src,
    const _Float16* __restrict__ w2h, _Float16* __restrict__ msgp)
{
  constexpr int EPB = 128;
  constexpr int MO = 64;
  constexpr int CT = 4;
  constexpr int CHB = CT * 1024;          // bytes per K32 chunk
  constexpr int XV = (MIP == 64) ? 2 : 1;
  constexpr int KH = (KCNT + 1) >> 1;
  constexpr int NG8 = KCNT / 8;           // full kl-groups of 8
  constexpr int JT = KCNT % 8;            // tail group size
  constexpr int NGT = (KCNT + 7) / 8;

  __shared__ _Float16 h16[NGT * EPB * 8]; // [g][edge][8]
  __shared__ float w1s[5 * 128 + 128];

  const int t = threadIdx.x;
  const int wave = t >> 6, lane = t & 63;
  const int l15 = lane & 15, q = lane >> 4;
  const int split = blockIdx.x / NBLK;
  const int e0 = (blockIdx.x % NBLK) * EPB;
  const int c0 = NCC * split;
  const int kg0 = KCNT * split;
  const char* wgp = (const char*)w2h + (size_t)c0 * CHB;

  // ---- edge attrs to regs; w1/b1 to LDS ----
  const int te = t & 127;
  float ear[5];
  {
    int eg = e0 + te; if (eg >= NE) eg = NE - 1;
#pragma unroll
    for (int j = 0; j < 5; ++j) ear[j] = ea[(size_t)eg * 5 + j];
  }
  for (int i = t; i < 768; i += 256) w1s[i] = (i < 640) ? w1[i] : b1[i - 640];
  __syncthreads();

  // ---- h phase: each edge's KCNT values split across thread halves ----
  {
    int kh = t >> 7;
    int klo = kh * KH;
    int khi = klo + KH; if (khi > KCNT) khi = KCNT;
    for (int kl = klo; kl < khi; ++kl) {
      int kg = kg0 + kl;
      float v;
      if (kg < 128) {
        v = w1s[640 + kg];
#pragma unroll
        for (int j = 0; j < 5; ++j) v = fmaf(ear[j], w1s[j * 128 + kg], v);
        v = fmaxf(v, 0.f);
      } else v = (kg == 128) ? 1.f : 0.f;
      h16[((kl >> 3) * EPB + te) * 8 + (kl & 7)] = (_Float16)v;
    }
  }
  __syncthreads();

  // ---- x fragments: 8 M-subtiles per wave (loaded after barrier to shorten live range) ----
  half8_t xf[8][XV];
#pragma unroll
  for (int m = 0; m < 8; ++m) {
    int eg = e0 + m * 16 + l15; if (eg >= NE) eg = NE - 1;
    const _Float16* xr = xe + (size_t)src[eg] * MIP;
    xf[m][0] = *(const half8_t*)(xr + q * 8);
    if constexpr (MIP == 64)
      xf[m][XV - 1] = *(const half8_t*)(xr + 32 + q * 8);
  }

  floatx4 acc[8];
#pragma unroll
  for (int m = 0; m < 8; ++m) acc[m] = (floatx4){0.f, 0.f, 0.f, 0.f};

  // wave's private W slice base: N-tile = wave
  const char* wq = wgp + (size_t)wave * 1024 + (size_t)lane * 16;

#pragma unroll
  for (int g = 0; g < NGT; ++g) {
    half8_t h8[8];
#pragma unroll
    for (int m = 0; m < 8; ++m)
      h8[m] = *(const half8_t*)(h16 + ((size_t)g * EPB + m * 16 + l15) * 8);
    const int jn = (g < NG8) ? 8 : JT;   // g is unroll-static -> jn folds to a constant
#pragma unroll
    for (int j = 0; j < 8; ++j) {
      if (j < jn) {
        const int kl = g * 8 + j;
        if constexpr (MIP == 64) {
#pragma unroll
          for (int hf = 0; hf < 2; ++hf) {
            const int cc = kl * 2 + hf;
            half8_t bf = *(const half8_t*)(wq + (size_t)cc * CHB);
#pragma unroll
            for (int m = 0; m < 8; ++m) {
              half8_t af = xf[m][hf] * h8[m][j];
              acc[m] = __builtin_amdgcn_mfma_f32_16x16x32_f16(af, bf, acc[m], 0, 0, 0);
            }
          }
        } else {
          const int cc = kl;
          half8_t bf = *(const half8_t*)(wq + (size_t)cc * CHB);
#pragma unroll
          for (int m = 0; m < 8; ++m) {
            half8_t af = xf[m][0] * h8[m][j];
            acc[m] = __builtin_amdgcn_mfma_f32_16x16x32_f16(af, bf, acc[m], 0, 0, 0);
          }
        }
      }
    }
  }

  // ---- epilogue: wave stores its 16-col slice for all 128 rows ----
  _Float16* mp = msgp + (size_t)split * NE * MO;
  const int n = wave * 16 + l15;
#pragma unroll
  for (int m = 0; m < 8; ++m) {
    int rowb = m * 16 + q * 4;
#pragma unroll
    for (int r = 0; r < 4; ++r) {
      int e = e0 + rowb + r;
      if (e < NE) mp[(size_t)e * MO + n] = (_Float16)acc[m][r];
    }
  }
}

// ---- gather: per node, sum CSR-listed edge partials (+root-GEMM +bias), ELU unless FINAL ----
template <int MIN_, int XST, int MO, int FINAL>
__global__ __launch_bounds__(256) void gather_kernel(
    const _Float16* __restrict__ e16in, const float* __restrict__ root,
    const float* __restrict__ bias, const int* __restrict__ row_ptr,
    const int* __restrict__ eids, const _Float16* __restrict__ msgp,
    _Float16* __restrict__ oute, float* __restrict__ outf)
{
  constexpr int NPB = 256 / MO;
  int n = blockIdx.x * NPB + threadIdx.x / MO;
  int o = threadIdx.x % MO;
  if (n >= NN) return;
  float a = bias[o];
#pragma unroll
  for (int i = 0; i < MIN_; ++i)
    a = fmaf((float)e16in[(size_t)n * XST + i], root[i * MO + o], a);
  int r0 = row_ptr[n], r1 = row_ptr[n + 1];
  for (int j = r0; j < r1; ++j) {
    int e = eids[j];
#pragma unroll
    for (int s = 0; s < NSPLIT; ++s)
      a += (float)msgp[((size_t)s * NE + e) * MO + o];
  }
  if constexpr (FINAL) {
    outf[(size_t)n * MO + o] = a;
  } else {
    float v = a > 0.f ? a : (expf(a) - 1.f);
    oute[(size_t)n * MO + o] = (_Float16)v;
  }
}

// ---- pooling (segment mean over sorted batch, fused ELU) + 3-layer FC head ----
__global__ __launch_bounds__(64) void pool_fc_kernel(
    const float* __restrict__ xn2, const int* __restrict__ batch,
    const float* __restrict__ f1w, const float* __restrict__ f1b,
    const float* __restrict__ f2w, const float* __restrict__ f2b,
    const float* __restrict__ f3w, const float* __restrict__ f3b,
    float* __restrict__ out)
{
  __shared__ float xg[64]; __shared__ float a1[32]; __shared__ float a2[16];
  int g = blockIdx.x, t = threadIdx.x;
  int lo = 0, hi = NN;
  while (lo < hi) { int m = (lo + hi) >> 1; if (batch[m] < g) lo = m + 1; else hi = m; }
  int start = lo; hi = NN;
  while (lo < hi) { int m = (lo + hi) >> 1; if (batch[m] <= g) lo = m + 1; else hi = m; }
  int end = lo;
  float acc = 0.f;
  for (int n = start; n < end; ++n) {
    float v = xn2[(size_t)n * 64 + t];
    acc += v > 0.f ? v : (expf(v) - 1.f);
  }
  float c = (end > start) ? (float)(end - start) : 1.f;
  xg[t] = acc / c;
  __syncthreads();
  if (t < 32) {
    float a = f1b[t];
    for (int i = 0; i < 64; ++i) a = fmaf(xg[i], f1w[i * 32 + t], a);
    a1[t] = a > 0.f ? a : (expf(a) - 1.f);
  }
  __syncthreads();
  if (t < 16) {
    float a = f2b[t];
    for (int i = 0; i < 32; ++i) a = fmaf(a1[i], f2w[i * 16 + t], a);
    a2[t] = a > 0.f ? a : (expf(a) - 1.f);
  }
  __syncthreads();
  if (t == 0) {
    float a = f3b[0];
    for (int i = 0; i < 16; ++i) a = fmaf(a2[i], f3w[i], a);
    out[g] = a;
  }
}

extern "C" void kernel_launch(void* const* d_in, const int* in_sizes, int n_in,
                              void* d_out, int out_size, void* d_ws, size_t ws_size,
                              hipStream_t stream)
{
  const float* x_in  = (const float*)d_in[0];
  const int*   ei    = (const int*)d_in[1];
  const float* ea    = (const float*)d_in[2];
  const int*   batch = (const int*)d_in[3];
  const float* W1[3] = {(const float*)d_in[4],  (const float*)d_in[10], (const float*)d_in[16]};
  const float* B1[3] = {(const float*)d_in[5],  (const float*)d_in[11], (const float*)d_in[17]};
  const float* W2[3] = {(const float*)d_in[6],  (const float*)d_in[12], (const float*)d_in[18]};
  const float* B2[3] = {(const float*)d_in[7],  (const float*)d_in[13], (const float*)d_in[19]};
  const float* RT[3] = {(const float*)d_in[8],  (const float*)d_in[14], (const float*)d_in[20]};
  const float* BS[3] = {(const float*)d_in[9],  (const float*)d_in[15], (const float*)d_in[21]};
  const float* f1w = (const float*)d_in[22]; const float* f1b = (const float*)d_in[23];
  const float* f2w = (const float*)d_in[24]; const float* f2b = (const float*)d_in[25];
  const float* f3w = (const float*)d_in[26]; const float* f3b = (const float*)d_in[27];

  char* ws = (char*)d_ws;
  size_t off = 0;
  auto alloc = [&](size_t bytes) { void* p = ws + off; off += (bytes + 255) & ~(size_t)255; return p; };
  float*    xn2   = (float*)alloc((size_t)NN * 64 * 4);
  _Float16* e16_0 = (_Float16*)alloc((size_t)NN * 16 * 2);
  _Float16* e16_1 = (_Float16*)alloc((size_t)NN * 32 * 2);
  _Float16* e16_2 = (_Float16*)alloc((size_t)NN * 64 * 2);
  _Float16* w2h0  = (_Float16*)alloc((size_t)68 * 2048);
  _Float16* w2h1  = (_Float16*)alloc((size_t)132 * 4096);
  _Float16* w2h2  = (_Float16*)alloc((size_t)264 * 4096);
  _Float16* msgp  = (_Float16*)alloc((size_t)NSPLIT * NE * 64 * 2);
  int*      deg     = (int*)alloc((size_t)NN * 4);
  int*      row_ptr = (int*)alloc((size_t)(NN + 1) * 4);
  int*      cursor  = (int*)alloc((size_t)NN * 4);
  int*      eids    = (int*)alloc((size_t)NE * 4);

  const int* srcp = ei;
  const int* dstp = ei + NE;

  prep_fused_kernel<<<1680 + (NN + 255) / 256, 256, 0, stream>>>(
      x_in, e16_0, W2[0], B2[0], w2h0, W2[1], B2[1], w2h1, W2[2], B2[2], w2h2, deg);
  deg_kernel<<<(NE + 255) / 256, 256, 0, stream>>>(dstp, deg);
  scan_kernel<<<1, 1024, 0, stream>>>(deg, row_ptr, cursor);
  fill_kernel<<<(NE + 255) / 256, 256, 0, stream>>>(dstp, cursor, eids);

  // ---- layer 0: R6 msg9, 17 chunks/split, KCNT=34 ----
  msg9_kernel<16, 32, 17, 34><<<NBLK * NSPLIT, 256, 0, stream>>>(
      ea, W1[0], B1[0], e16_0, srcp, w2h0, msgp);
  gather_kernel<13, 16, 32, 0><<<(NN + 7) / 8, 256, 0, stream>>>(
      e16_0, RT[0], BS[0], row_ptr, eids, msgp, e16_1, xn2);

  // ---- layer 1: msgN, 33 chunks/split, KCNT=33 ----
  msgN_kernel<32, 33, 33><<<NBLK * NSPLIT, 256, 0, stream>>>(
      ea, W1[1], B1[1], e16_1, srcp, w2h1, msgp);
  gather_kernel<32, 32, 64, 0><<<(NN + 3) / 4, 256, 0, stream>>>(
      e16_1, RT[1], BS[1], row_ptr, eids, msgp, e16_2, xn2);

  // ---- layer 2: msgN, 66 chunks/split, KCNT=33 ----
  msgN_kernel<64, 66, 33><<<NBLK * NSPLIT, 256, 0, stream>>>(
      ea, W1[2], B1[2], e16_2, srcp, w2h2, msgp);
  gather_kernel<64, 64, 64, 1><<<(NN + 3) / 4, 256, 0, stream>>>(
      e16_2, RT[2], BS[2], row_ptr, eids, msgp, e16_2, xn2);

  pool_fc_kernel<<<NG, 64, 0, stream>>>(xn2, batch, f1w, f1b, f2w, f2b, f3w, f3b, (float*)d_out);
}

// Round 9
// 297.454 us; speedup vs baseline: 1.0463x; 1.0316x over previous
//
#include <hip/hip_runtime.h>
#include <stdint.h>
#include <math.h>

typedef _Float16 half8_t __attribute__((ext_vector_type(8)));
typedef float floatx4 __attribute__((ext_vector_type(4)));

#define NN 20000
#define NE 40000
#define NG 1000
#define NBLK 313      // ceil(NE/128)  -- 128 edges per block
#define NSPLIT 4

// ---- fused prep: [0,1250) x0->e16 pad ; [1250,1680) w2 -> B-frag images ; [1680..) deg=0 ----
// Chunk counts (NSPLIT=4): L0 = 68 (4x17), L1 = 132 (4x33), L2 = 264 (4x66).
__global__ __launch_bounds__(256) void prep_fused_kernel(
    const float* __restrict__ x, _Float16* __restrict__ e16,
    const float* __restrict__ w2a, const float* __restrict__ b2a, _Float16* __restrict__ oa,
    const float* __restrict__ w2b, const float* __restrict__ b2b, _Float16* __restrict__ ob,
    const float* __restrict__ w2c, const float* __restrict__ b2c, _Float16* __restrict__ oc,
    int* __restrict__ deg)
{
  if (blockIdx.x < 1250) {
    int idx = blockIdx.x * 256 + threadIdx.x;   // over NN*16
    int n = idx >> 4, i = idx & 15;
    e16[idx] = (i < 13) ? (_Float16)x[(size_t)n * 13 + i] : (_Float16)0.f;
    return;
  }
  if (blockIdx.x >= 1680) {
    int n = (blockIdx.x - 1680) * 256 + threadIdx.x;
    if (n < NN) deg[n] = 0;
    return;
  }
  const int TOT0 = 68 * 2 * 64, TOT1 = 132 * 4 * 64, TOT2 = 264 * 4 * 64;
  int idx = (blockIdx.x - 1250) * 256 + threadIdx.x;
  const float *w2, *b2; _Float16* op; int mi, mo, mpsh, CT;
  if (idx < TOT0) { w2 = w2a; b2 = b2a; op = oa; mi = 13; mo = 32; mpsh = 4; CT = 2; }
  else if (idx < TOT0 + TOT1) { idx -= TOT0; w2 = w2b; b2 = b2b; op = ob; mi = 32; mo = 64; mpsh = 5; CT = 4; }
  else if (idx < TOT0 + TOT1 + TOT2) { idx -= TOT0 + TOT1; w2 = w2c; b2 = b2c; op = oc; mi = 64; mo = 64; mpsh = 6; CT = 4; }
  else return;
  int l = idx & 63;
  int ct = (idx >> 6) % CT;
  int c = idx / (64 * CT);
  int q = l >> 4;
  int n = ct * 16 + (l & 15);
  int mask = (1 << mpsh) - 1;
  half8_t v;
#pragma unroll
  for (int j = 0; j < 8; ++j) {
    int r = c * 32 + q * 8 + j;
    int k = r >> mpsh, i = r & mask;
    float f = 0.f;
    if (i < mi) {
      if (k < 128) f = w2[(size_t)(k * mi + i) * mo + n];
      else if (k == 128) f = b2[(size_t)i * mo + n];
    }
    v[j] = (_Float16)f;
  }
  *(half8_t*)(op + (size_t)idx * 8) = v;
}

// ---- CSR build: histogram, parallel scan, fill ----
__global__ __launch_bounds__(256) void deg_kernel(const int* __restrict__ dst, int* __restrict__ deg) {
  int e = blockIdx.x * 256 + threadIdx.x;
  if (e < NE) atomicAdd(&deg[dst[e]], 1);
}

__global__ __launch_bounds__(1024) void scan_kernel(
    const int* __restrict__ deg, int* __restrict__ row_ptr, int* __restrict__ cursor)
{
  constexpr int CH = 20;                 // 1024*20 = 20480 >= NN+1
  __shared__ int wsum[16];
  int t = threadIdx.x;
  int lane = t & 63, w = t >> 6;
  int base = t * CH;
  int local[CH];
#pragma unroll
  for (int i = 0; i < CH; ++i) {
    int n = base + i;
    local[i] = (n < NN) ? deg[n] : 0;
  }
  int s = 0;
#pragma unroll
  for (int i = 0; i < CH; ++i) s += local[i];
  int sc = s;
#pragma unroll
  for (int d = 1; d < 64; d <<= 1) {
    int v = __shfl_up(sc, d, 64);
    if (lane >= d) sc += v;
  }
  if (lane == 63) wsum[w] = sc;
  __syncthreads();
  if (w == 0 && lane < 16) {
    int v = wsum[lane];
    int scc = v;
#pragma unroll
    for (int d = 1; d < 16; d <<= 1) {
      int u = __shfl_up(scc, d, 64);
      if (lane >= d) scc += u;
    }
    wsum[lane] = scc - v;                // exclusive wave prefix
  }
  __syncthreads();
  int run = wsum[w] + (sc - s);          // exclusive prefix for this thread
#pragma unroll
  for (int i = 0; i < CH; ++i) {
    int n = base + i;
    if (n < NN) { row_ptr[n] = run; cursor[n] = run; run += local[i]; }
    else if (n == NN) row_ptr[NN] = run;
  }
}

__global__ __launch_bounds__(256) void fill_kernel(
    const int* __restrict__ dst, int* __restrict__ cursor, int* __restrict__ eids)
{
  int e = blockIdx.x * 256 + threadIdx.x;
  if (e < NE) { int p = atomicAdd(&cursor[dst[e]], 1); eids[p] = e; }
}

// ---------------- L0 message kernel: R6 structure (proven), LDS W staging ----------------
template <int MIP, int MO, int NCC, int KCNT>
__global__ __launch_bounds__(256, 4) void msg9_kernel(
    const float* __restrict__ ea, const float* __restrict__ w1,
    const float* __restrict__ b1, const _Float16* __restrict__ xe,
    const int* __restrict__ src,
    const _Float16* __restrict__ w2h, _Float16* __restrict__ msgp)
{
  constexpr int EPB = 128;                // edges per block
  constexpr int CT = MO / 16;
  constexpr int CHB = CT * 1024;          // BYTES per K32-chunk of W image
  constexpr int XV = (MIP == 64) ? 2 : 1;
  constexpr int KH = (KCNT + 1) >> 1;     // h k-values per thread-half

  __shared__ uint4 wsb[2][CHB / 16];
  __shared__ _Float16 h16[KCNT * EPB];    // transposed: h16[kl][edge]
  __shared__ float w1s[5 * 128 + 128];

  const int t = threadIdx.x;
  const int wave = t >> 6, lane = t & 63;
  const int l15 = lane & 15, q = lane >> 4;
  const int split = blockIdx.x / NBLK;
  const int e0 = (blockIdx.x % NBLK) * EPB;
  const int c0 = NCC * split;
  const int kg0 = KCNT * split;

  // ---- W prefetch: first two chunks into named registers ----
  const char* wgp = (const char*)w2h + (size_t)c0 * CHB;
  uint4 ra4, rb4; uint2 ra2, rb2;
  if constexpr (CT == 4) {
    ra4 = *(const uint4*)(wgp + t * 16);
    rb4 = *(const uint4*)(wgp + CHB + t * 16);
  } else {
    ra2 = *(const uint2*)(wgp + t * 8);
    rb2 = *(const uint2*)(wgp + CHB + t * 8);
  }

  // ---- x fragments direct from global (2 M-subtiles per wave) ----
  const int wbase = wave * 32;
  half8_t xf[2][XV];
#pragma unroll
  for (int s = 0; s < 2; ++s) {
    int eg = e0 + wbase + s * 16 + l15; if (eg >= NE) eg = NE - 1;
    const _Float16* xr = xe + (size_t)src[eg] * MIP;
    int i0 = (MIP == 16) ? (q & 1) * 8 : q * 8;
    xf[s][0] = *(const half8_t*)(xr + i0);
    if constexpr (MIP == 64)
      xf[s][XV - 1] = *(const half8_t*)(xr + 32 + q * 8);
  }

  // ---- edge attrs to regs (thread-half te owns edge e0+te); w1/b1 to LDS ----
  const int te = t & 127;
  float ear[5];
  {
    int eg = e0 + te; if (eg >= NE) eg = NE - 1;
#pragma unroll
    for (int j = 0; j < 5; ++j) ear[j] = ea[(size_t)eg * 5 + j];
  }
  for (int i = t; i < 768; i += 256) w1s[i] = (i < 640) ? w1[i] : b1[i - 640];
  __syncthreads();

  // ---- h phase: each edge's KCNT values split across thread halves ----
  {
    int kh = t >> 7;
    int klo = kh * KH;
    int khi = klo + KH; if (khi > KCNT) khi = KCNT;
    for (int kl = klo; kl < khi; ++kl) {
      int kg = kg0 + kl;
      float v;
      if (kg < 128) {
        v = w1s[640 + kg];
#pragma unroll
        for (int j = 0; j < 5; ++j) v = fmaf(ear[j], w1s[j * 128 + kg], v);
        v = fmaxf(v, 0.f);
      } else v = (kg == 128) ? 1.f : 0.f;
      h16[kl * EPB + te] = (_Float16)v;
    }
  }
  __syncthreads();

  // ---- K loop: 1 barrier/chunk, LDS double-buffer, 2-deep register prefetch ----
  floatx4 acc[2][CT];
#pragma unroll
  for (int s = 0; s < 2; ++s)
#pragma unroll
    for (int b = 0; b < CT; ++b) acc[s][b] = (floatx4){0.f, 0.f, 0.f, 0.f};

#pragma unroll 2
  for (int cc = 0; cc < NCC; ++cc) {
    const bool odd = (cc & 1) != 0;
    if constexpr (CT == 4) wsb[cc & 1][t] = odd ? rb4 : ra4;
    else ((uint2*)wsb[cc & 1])[t] = odd ? rb2 : ra2;
    if (cc + 2 < NCC) {
      const char* np = wgp + (size_t)(cc + 2) * CHB;
      if constexpr (CT == 4) {
        if (odd) rb4 = *(const uint4*)(np + t * 16); else ra4 = *(const uint4*)(np + t * 16);
      } else {
        if (odd) rb2 = *(const uint2*)(np + t * 8); else ra2 = *(const uint2*)(np + t * 8);
      }
    }
    __syncthreads();
    const _Float16* wb = (const _Float16*)wsb[cc & 1];
    half8_t bf[CT];
#pragma unroll
    for (int b = 0; b < CT; ++b)
      bf[b] = *(const half8_t*)(wb + (b * 64 + lane) * 8);
    int kl;
    if constexpr (MIP == 64) kl = cc >> 1;
    else if constexpr (MIP == 32) kl = cc;
    else kl = 2 * cc + (q >> 1);
#pragma unroll
    for (int s = 0; s < 2; ++s) {
      _Float16 hv = h16[kl * EPB + wbase + s * 16 + l15];
      half8_t af;
      if constexpr (MIP == 64) af = xf[s][cc & 1] * hv;
      else af = xf[s][0] * hv;
#pragma unroll
      for (int b = 0; b < CT; ++b)
        acc[s][b] = __builtin_amdgcn_mfma_f32_16x16x32_f16(af, bf[b], acc[s][b], 0, 0, 0);
    }
  }

  // ---- epilogue: plain fp16 partial stores, no atomics ----
  _Float16* mp = msgp + (size_t)split * NE * MO;
#pragma unroll
  for (int s = 0; s < 2; ++s) {
    int rowb = wbase + s * 16 + q * 4;
#pragma unroll
    for (int b = 0; b < CT; ++b) {
      int n = b * 16 + l15;
#pragma unroll
      for (int r = 0; r < 4; ++r) {
        int row = rowb + r;
        int e = e0 + row;
        if (e < NE) mp[(size_t)e * MO + n] = (_Float16)acc[s][b][r];
      }
    }
  }
}

// ---------------- L1/L2 message kernel: 2M x 2N wave split (MO=64) ----------------
// Wave (mw,nw): rows mw*64 + s*16 (4 M-subtiles), cols nw*32 + b*16 (2 B-fragments).
// Balances the pipes: LDS W-read 2KB/wave/chunk (2x dup), af VALU 4 mults/wave/chunk (2x dup),
// MFMA 8/wave/chunk. Staging machinery identical to msg9 (proven race-free).
template <int MIP, int NCC, int KCNT>
__global__ __launch_bounds__(256, 4) void msgH_kernel(
    const float* __restrict__ ea, const float* __restrict__ w1,
    const float* __restrict__ b1, const _Float16* __restrict__ xe,
    const int* __restrict__ src,
    const _Float16* __restrict__ w2h, _Float16* __restrict__ msgp)
{
  constexpr int EPB = 128;
  constexpr int MO = 64;
  constexpr int CHB = 4096;               // bytes per K32 chunk (4 fragments)
  constexpr int XV = (MIP == 64) ? 2 : 1;
  constexpr int KH = (KCNT + 1) >> 1;

  __shared__ uint4 wsb[2][CHB / 16];
  __shared__ _Float16 h16[KCNT * EPB];    // transposed: h16[kl][edge]
  __shared__ float w1s[5 * 128 + 128];

  const int t = threadIdx.x;
  const int wave = t >> 6, lane = t & 63;
  const int l15 = lane & 15, q = lane >> 4;
  const int mw = wave >> 1;               // M half: rows mw*64..mw*64+63
  const int nw = wave & 1;                // N half: cols nw*32..nw*32+31
  const int split = blockIdx.x / NBLK;
  const int e0 = (blockIdx.x % NBLK) * EPB;
  const int c0 = NCC * split;
  const int kg0 = KCNT * split;

  // ---- W prefetch: first two chunks into named registers ----
  const char* wgp = (const char*)w2h + (size_t)c0 * CHB;
  uint4 ra4 = *(const uint4*)(wgp + t * 16);
  uint4 rb4 = *(const uint4*)(wgp + CHB + t * 16);

  // ---- x fragments direct from global (4 M-subtiles per wave, rows mw*64+) ----
  half8_t xf[4][XV];
#pragma unroll
  for (int s = 0; s < 4; ++s) {
    int eg = e0 + mw * 64 + s * 16 + l15; if (eg >= NE) eg = NE - 1;
    const _Float16* xr = xe + (size_t)src[eg] * MIP;
    xf[s][0] = *(const half8_t*)(xr + q * 8);
    if constexpr (MIP == 64)
      xf[s][XV - 1] = *(const half8_t*)(xr + 32 + q * 8);
  }

  // ---- edge attrs to regs (thread-half te owns edge e0+te); w1/b1 to LDS ----
  const int te = t & 127;
  float ear[5];
  {
    int eg = e0 + te; if (eg >= NE) eg = NE - 1;
#pragma unroll
    for (int j = 0; j < 5; ++j) ear[j] = ea[(size_t)eg * 5 + j];
  }
  for (int i = t; i < 768; i += 256) w1s[i] = (i < 640) ? w1[i] : b1[i - 640];
  __syncthreads();

  // ---- h phase: each edge's KCNT values split across thread halves ----
  {
    int kh = t >> 7;
    int klo = kh * KH;
    int khi = klo + KH; if (khi > KCNT) khi = KCNT;
    for (int kl = klo; kl < khi; ++kl) {
      int kg = kg0 + kl;
      float v;
      if (kg < 128) {
        v = w1s[640 + kg];
#pragma unroll
        for (int j = 0; j < 5; ++j) v = fmaf(ear[j], w1s[j * 128 + kg], v);
        v = fmaxf(v, 0.f);
      } else v = (kg == 128) ? 1.f : 0.f;
      h16[kl * EPB + te] = (_Float16)v;
    }
  }
  __syncthreads();

  // ---- K loop: 1 barrier/chunk, LDS double-buffer, 2-deep register prefetch ----
  floatx4 acc[4][2];
#pragma unroll
  for (int s = 0; s < 4; ++s)
#pragma unroll
    for (int b = 0; b < 2; ++b) acc[s][b] = (floatx4){0.f, 0.f, 0.f, 0.f};

#pragma unroll 2
  for (int cc = 0; cc < NCC; ++cc) {
    const bool odd = (cc & 1) != 0;
    wsb[cc & 1][t] = odd ? rb4 : ra4;
    if (cc + 2 < NCC) {
      const char* np = wgp + (size_t)(cc + 2) * CHB;
      if (odd) rb4 = *(const uint4*)(np + t * 16); else ra4 = *(const uint4*)(np + t * 16);
    }
    __syncthreads();
    const _Float16* wb = (const _Float16*)wsb[cc & 1];
    half8_t bf[2];
#pragma unroll
    for (int b = 0; b < 2; ++b)
      bf[b] = *(const half8_t*)(wb + ((nw * 2 + b) * 64 + lane) * 8);
    int kl;
    if constexpr (MIP == 64) kl = cc >> 1;
    else kl = cc;
#pragma unroll
    for (int s = 0; s < 4; ++s) {
      _Float16 hv = h16[kl * EPB + mw * 64 + s * 16 + l15];
      half8_t af;
      if constexpr (MIP == 64) af = xf[s][cc & 1] * hv;
      else af = xf[s][0] * hv;
#pragma unroll
      for (int b = 0; b < 2; ++b)
        acc[s][b] = __builtin_amdgcn_mfma_f32_16x16x32_f16(af, bf[b], acc[s][b], 0, 0, 0);
    }
  }

  // ---- epilogue: wave stores its 64-row x 32-col quadrant ----
  _Float16* mp = msgp + (size_t)split * NE * MO;
#pragma unroll
  for (int s = 0; s < 4; ++s) {
    int rowb = mw * 64 + s * 16 + q * 4;
#pragma unroll
    for (int b = 0; b < 2; ++b) {
      int n = nw * 32 + b * 16 + l15;
#pragma unroll
      for (int r = 0; r < 4; ++r) {
        int e = e0 + rowb + r;
        if (e < NE) mp[(size_t)e * MO + n] = (_Float16)acc[s][b][r];
      }
    }
  }
}

// ---- gather: per node, sum CSR-listed edge partials (+root-GEMM +bias), ELU unless FINAL ----
template <int MIN_, int XST, int MO, int FINAL>
__global__ __launch_bounds__(256) void gather_kernel(
    const _Float16* __restrict__ e16in, const float* __restrict__ root,
    const float* __restrict__ bias, const int* __restrict__ row_ptr,
    const int* __restrict__ eids, const _Float16* __restrict__ msgp,
    _Float16* __restrict__ oute, float* __restrict__ outf)
{
  constexpr int NPB = 256 / MO;
  int n = blockIdx.x * NPB + threadIdx.x / MO;
  int o = threadIdx.x % MO;
  if (n >= NN) return;
  float a = bias[o];
#pragma unroll
  for (int i = 0; i < MIN_; ++i)
    a = fmaf((float)e16in[(size_t)n * XST + i], root[i * MO + o], a);
  int r0 = row_ptr[n], r1 = row_ptr[n + 1];
  for (int j = r0; j < r1; ++j) {
    int e = eids[j];
#pragma unroll
    for (int s = 0; s < NSPLIT; ++s)
      a += (float)msgp[((size_t)s * NE + e) * MO + o];
  }
  if constexpr (FINAL) {
    outf[(size_t)n * MO + o] = a;
  } else {
    float v = a > 0.f ? a : (expf(a) - 1.f);
    oute[(size_t)n * MO + o] = (_Float16)v;
  }
}

// ---- pooling (segment mean over sorted batch, fused ELU) + 3-layer FC head ----
__global__ __launch_bounds__(64) void pool_fc_kernel(
    const float* __restrict__ xn2, const int* __restrict__ batch,
    const float* __restrict__ f1w, const float* __restrict__ f1b,
    const float* __restrict__ f2w, const float* __restrict__ f2b,
    const float* __restrict__ f3w, const float* __restrict__ f3b,
    float* __restrict__ out)
{
  __shared__ float xg[64]; __shared__ float a1[32]; __shared__ float a2[16];
  int g = blockIdx.x, t = threadIdx.x;
  int lo = 0, hi = NN;
  while (lo < hi) { int m = (lo + hi) >> 1; if (batch[m] < g) lo = m + 1; else hi = m; }
  int start = lo; hi = NN;
  while (lo < hi) { int m = (lo + hi) >> 1; if (batch[m] <= g) lo = m + 1; else hi = m; }
  int end = lo;
  float acc = 0.f;
  for (int n = start; n < end; ++n) {
    float v = xn2[(size_t)n * 64 + t];
    acc += v > 0.f ? v : (expf(v) - 1.f);
  }
  float c = (end > start) ? (float)(end - start) : 1.f;
  xg[t] = acc / c;
  __syncthreads();
  if (t < 32) {
    float a = f1b[t];
    for (int i = 0; i < 64; ++i) a = fmaf(xg[i], f1w[i * 32 + t], a);
    a1[t] = a > 0.f ? a : (expf(a) - 1.f);
  }
  __syncthreads();
  if (t < 16) {
    float a = f2b[t];
    for (int i = 0; i < 32; ++i) a = fmaf(a1[i], f2w[i * 16 + t], a);
    a2[t] = a > 0.f ? a : (expf(a) - 1.f);
  }
  __syncthreads();
  if (t == 0) {
    float a = f3b[0];
    for (int i = 0; i < 16; ++i) a = fmaf(a2[i], f3w[i], a);
    out[g] = a;
  }
}

extern "C" void kernel_launch(void* const* d_in, const int* in_sizes, int n_in,
                              void* d_out, int out_size, void* d_ws, size_t ws_size,
                              hipStream_t stream)
{
  const float* x_in  = (const float*)d_in[0];
  const int*   ei    = (const int*)d_in[1];
  const float* ea    = (const float*)d_in[2];
  const int*   batch = (const int*)d_in[3];
  const float* W1[3] = {(const float*)d_in[4],  (const float*)d_in[10], (const float*)d_in[16]};
  const float* B1[3] = {(const float*)d_in[5],  (const float*)d_in[11], (const float*)d_in[17]};
  const float* W2[3] = {(const float*)d_in[6],  (const float*)d_in[12], (const float*)d_in[18]};
  const float* B2[3] = {(const float*)d_in[7],  (const float*)d_in[13], (const float*)d_in[19]};
  const float* RT[3] = {(const float*)d_in[8],  (const float*)d_in[14], (const float*)d_in[20]};
  const float* BS[3] = {(const float*)d_in[9],  (const float*)d_in[15], (const float*)d_in[21]};
  const float* f1w = (const float*)d_in[22]; const float* f1b = (const float*)d_in[23];
  const float* f2w = (const float*)d_in[24]; const float* f2b = (const float*)d_in[25];
  const float* f3w = (const float*)d_in[26]; const float* f3b = (const float*)d_in[27];

  char* ws = (char*)d_ws;
  size_t off = 0;
  auto alloc = [&](size_t bytes) { void* p = ws + off; off += (bytes + 255) & ~(size_t)255; return p; };
  float*    xn2   = (float*)alloc((size_t)NN * 64 * 4);
  _Float16* e16_0 = (_Float16*)alloc((size_t)NN * 16 * 2);
  _Float16* e16_1 = (_Float16*)alloc((size_t)NN * 32 * 2);
  _Float16* e16_2 = (_Float16*)alloc((size_t)NN * 64 * 2);
  _Float16* w2h0  = (_Float16*)alloc((size_t)68 * 2048);
  _Float16* w2h1  = (_Float16*)alloc((size_t)132 * 4096);
  _Float16* w2h2  = (_Float16*)alloc((size_t)264 * 4096);
  _Float16* msgp  = (_Float16*)alloc((size_t)NSPLIT * NE * 64 * 2);
  int*      deg     = (int*)alloc((size_t)NN * 4);
  int*      row_ptr = (int*)alloc((size_t)(NN + 1) * 4);
  int*      cursor  = (int*)alloc((size_t)NN * 4);
  int*      eids    = (int*)alloc((size_t)NE * 4);

  const int* srcp = ei;
  const int* dstp = ei + NE;

  prep_fused_kernel<<<1680 + (NN + 255) / 256, 256, 0, stream>>>(
      x_in, e16_0, W2[0], B2[0], w2h0, W2[1], B2[1], w2h1, W2[2], B2[2], w2h2, deg);
  deg_kernel<<<(NE + 255) / 256, 256, 0, stream>>>(dstp, deg);
  scan_kernel<<<1, 1024, 0, stream>>>(deg, row_ptr, cursor);
  fill_kernel<<<(NE + 255) / 256, 256, 0, stream>>>(dstp, cursor, eids);

  // ---- layer 0: R6 msg9, 17 chunks/split, KCNT=34 ----
  msg9_kernel<16, 32, 17, 34><<<NBLK * NSPLIT, 256, 0, stream>>>(
      ea, W1[0], B1[0], e16_0, srcp, w2h0, msgp);
  gather_kernel<13, 16, 32, 0><<<(NN + 7) / 8, 256, 0, stream>>>(
      e16_0, RT[0], BS[0], row_ptr, eids, msgp, e16_1, xn2);

  // ---- layer 1: msgH 2Mx2N, 33 chunks/split, KCNT=33 ----
  msgH_kernel<32, 33, 33><<<NBLK * NSPLIT, 256, 0, stream>>>(
      ea, W1[1], B1[1], e16_1, srcp, w2h1, msgp);
  gather_kernel<32, 32, 64, 0><<<(NN + 3) / 4, 256, 0, stream>>>(
      e16_1, RT[1], BS[1], row_ptr, eids, msgp, e16_2, xn2);

  // ---- layer 2: msgH 2Mx2N, 66 chunks/split, KCNT=33 ----
  msgH_kernel<64, 66, 33><<<NBLK * NSPLIT, 256, 0, stream>>>(
      ea, W1[2], B1[2], e16_2, srcp, w2h2, msgp);
  gather_kernel<64, 64, 64, 1><<<(NN + 3) / 4, 256, 0, stream>>>(
      e16_2, RT[2], BS[2], row_ptr, eids, msgp, e16_2, xn2);

  pool_fc_kernel<<<NG, 64, 0, stream>>>(xn2, batch, f1w, f1b, f2w, f2b, f3w, f3b, (float*)d_out);
}

// Round 10
// 296.169 us; speedup vs baseline: 1.0509x; 1.0043x over previous
//
#include <hip/hip_runtime.h>
#include <stdint.h>
#include <math.h>

typedef _Float16 half8_t __attribute__((ext_vector_type(8)));
typedef float floatx4 __attribute__((ext_vector_type(4)));

#define NN 20000
#define NE 40000
#define NG 1000
#define NBLK 313      // ceil(NE/128)  -- 128 edges per block
#define NSPLIT 4

// ---- fused prep: [0,1250) x0->e16 pad ; [1250,1684) w2 -> B-frag images ; [1684..) deg=0 ----
// Chunk counts (NSPLIT=4): L0 = 68 (4x17), L1 = 136 (4x34, padded even), L2 = 264 (4x66).
__global__ __launch_bounds__(256) void prep_fused_kernel(
    const float* __restrict__ x, _Float16* __restrict__ e16,
    const float* __restrict__ w2a, const float* __restrict__ b2a, _Float16* __restrict__ oa,
    const float* __restrict__ w2b, const float* __restrict__ b2b, _Float16* __restrict__ ob,
    const float* __restrict__ w2c, const float* __restrict__ b2c, _Float16* __restrict__ oc,
    int* __restrict__ deg)
{
  if (blockIdx.x < 1250) {
    int idx = blockIdx.x * 256 + threadIdx.x;   // over NN*16
    int n = idx >> 4, i = idx & 15;
    e16[idx] = (i < 13) ? (_Float16)x[(size_t)n * 13 + i] : (_Float16)0.f;
    return;
  }
  if (blockIdx.x >= 1684) {
    int n = (blockIdx.x - 1684) * 256 + threadIdx.x;
    if (n < NN) deg[n] = 0;
    return;
  }
  const int TOT0 = 68 * 2 * 64, TOT1 = 136 * 4 * 64, TOT2 = 264 * 4 * 64;
  int idx = (blockIdx.x - 1250) * 256 + threadIdx.x;
  const float *w2, *b2; _Float16* op; int mi, mo, mpsh, CT;
  if (idx < TOT0) { w2 = w2a; b2 = b2a; op = oa; mi = 13; mo = 32; mpsh = 4; CT = 2; }
  else if (idx < TOT0 + TOT1) { idx -= TOT0; w2 = w2b; b2 = b2b; op = ob; mi = 32; mo = 64; mpsh = 5; CT = 4; }
  else if (idx < TOT0 + TOT1 + TOT2) { idx -= TOT0 + TOT1; w2 = w2c; b2 = b2c; op = oc; mi = 64; mo = 64; mpsh = 6; CT = 4; }
  else return;
  int l = idx & 63;
  int ct = (idx >> 6) % CT;
  int c = idx / (64 * CT);
  int q = l >> 4;
  int n = ct * 16 + (l & 15);
  int mask = (1 << mpsh) - 1;
  half8_t v;
#pragma unroll
  for (int j = 0; j < 8; ++j) {
    int r = c * 32 + q * 8 + j;
    int k = r >> mpsh, i = r & mask;
    float f = 0.f;
    if (i < mi) {
      if (k < 128) f = w2[(size_t)(k * mi + i) * mo + n];
      else if (k == 128) f = b2[(size_t)i * mo + n];
    }
    v[j] = (_Float16)f;
  }
  *(half8_t*)(op + (size_t)idx * 8) = v;
}

// ---- CSR build: histogram, parallel scan, fill ----
__global__ __launch_bounds__(256) void deg_kernel(const int* __restrict__ dst, int* __restrict__ deg) {
  int e = blockIdx.x * 256 + threadIdx.x;
  if (e < NE) atomicAdd(&deg[dst[e]], 1);
}

__global__ __launch_bounds__(1024) void scan_kernel(
    const int* __restrict__ deg, int* __restrict__ row_ptr, int* __restrict__ cursor)
{
  constexpr int CH = 20;                 // 1024*20 = 20480 >= NN+1
  __shared__ int wsum[16];
  int t = threadIdx.x;
  int lane = t & 63, w = t >> 6;
  int base = t * CH;
  int local[CH];
#pragma unroll
  for (int i = 0; i < CH; ++i) {
    int n = base + i;
    local[i] = (n < NN) ? deg[n] : 0;
  }
  int s = 0;
#pragma unroll
  for (int i = 0; i < CH; ++i) s += local[i];
  int sc = s;
#pragma unroll
  for (int d = 1; d < 64; d <<= 1) {
    int v = __shfl_up(sc, d, 64);
    if (lane >= d) sc += v;
  }
  if (lane == 63) wsum[w] = sc;
  __syncthreads();
  if (w == 0 && lane < 16) {
    int v = wsum[lane];
    int scc = v;
#pragma unroll
    for (int d = 1; d < 16; d <<= 1) {
      int u = __shfl_up(scc, d, 64);
      if (lane >= d) scc += u;
    }
    wsum[lane] = scc - v;                // exclusive wave prefix
  }
  __syncthreads();
  int run = wsum[w] + (sc - s);          // exclusive prefix for this thread
#pragma unroll
  for (int i = 0; i < CH; ++i) {
    int n = base + i;
    if (n < NN) { row_ptr[n] = run; cursor[n] = run; run += local[i]; }
    else if (n == NN) row_ptr[NN] = run;
  }
}

__global__ __launch_bounds__(256) void fill_kernel(
    const int* __restrict__ dst, int* __restrict__ cursor, int* __restrict__ eids)
{
  int e = blockIdx.x * 256 + threadIdx.x;
  if (e < NE) { int p = atomicAdd(&cursor[dst[e]], 1); eids[p] = e; }
}

// ---------------- L0 message kernel: R6 structure (proven best), LDS W staging ----------------
template <int MIP, int MO, int NCC, int KCNT>
__global__ __launch_bounds__(256, 4) void msg9_kernel(
    const float* __restrict__ ea, const float* __restrict__ w1,
    const float* __restrict__ b1, const _Float16* __restrict__ xe,
    const int* __restrict__ src,
    const _Float16* __restrict__ w2h, _Float16* __restrict__ msgp)
{
  constexpr int EPB = 128;                // edges per block
  constexpr int CT = MO / 16;
  constexpr int CHB = CT * 1024;          // BYTES per K32-chunk of W image
  constexpr int XV = (MIP == 64) ? 2 : 1;
  constexpr int KH = (KCNT + 1) >> 1;     // h k-values per thread-half

  __shared__ uint4 wsb[2][CHB / 16];
  __shared__ _Float16 h16[KCNT * EPB];    // transposed: h16[kl][edge]
  __shared__ float w1s[5 * 128 + 128];

  const int t = threadIdx.x;
  const int wave = t >> 6, lane = t & 63;
  const int l15 = lane & 15, q = lane >> 4;
  const int split = blockIdx.x / NBLK;
  const int e0 = (blockIdx.x % NBLK) * EPB;
  const int c0 = NCC * split;
  const int kg0 = KCNT * split;

  // ---- W prefetch: first two chunks into named registers ----
  const char* wgp = (const char*)w2h + (size_t)c0 * CHB;
  uint4 ra4, rb4; uint2 ra2, rb2;
  if constexpr (CT == 4) {
    ra4 = *(const uint4*)(wgp + t * 16);
    rb4 = *(const uint4*)(wgp + CHB + t * 16);
  } else {
    ra2 = *(const uint2*)(wgp + t * 8);
    rb2 = *(const uint2*)(wgp + CHB + t * 8);
  }

  // ---- x fragments direct from global (2 M-subtiles per wave) ----
  const int wbase = wave * 32;
  half8_t xf[2][XV];
#pragma unroll
  for (int s = 0; s < 2; ++s) {
    int eg = e0 + wbase + s * 16 + l15; if (eg >= NE) eg = NE - 1;
    const _Float16* xr = xe + (size_t)src[eg] * MIP;
    int i0 = (MIP == 16) ? (q & 1) * 8 : q * 8;
    xf[s][0] = *(const half8_t*)(xr + i0);
    if constexpr (MIP == 64)
      xf[s][XV - 1] = *(const half8_t*)(xr + 32 + q * 8);
  }

  // ---- edge attrs to regs (thread-half te owns edge e0+te); w1/b1 to LDS ----
  const int te = t & 127;
  float ear[5];
  {
    int eg = e0 + te; if (eg >= NE) eg = NE - 1;
#pragma unroll
    for (int j = 0; j < 5; ++j) ear[j] = ea[(size_t)eg * 5 + j];
  }
  for (int i = t; i < 768; i += 256) w1s[i] = (i < 640) ? w1[i] : b1[i - 640];
  __syncthreads();

  // ---- h phase: each edge's KCNT values split across thread halves ----
  {
    int kh = t >> 7;
    int klo = kh * KH;
    int khi = klo + KH; if (khi > KCNT) khi = KCNT;
    for (int kl = klo; kl < khi; ++kl) {
      int kg = kg0 + kl;
      float v;
      if (kg < 128) {
        v = w1s[640 + kg];
#pragma unroll
        for (int j = 0; j < 5; ++j) v = fmaf(ear[j], w1s[j * 128 + kg], v);
        v = fmaxf(v, 0.f);
      } else v = (kg == 128) ? 1.f : 0.f;
      h16[kl * EPB + te] = (_Float16)v;
    }
  }
  __syncthreads();

  // ---- K loop: 1 barrier/chunk, LDS double-buffer, 2-deep register prefetch ----
  floatx4 acc[2][CT];
#pragma unroll
  for (int s = 0; s < 2; ++s)
#pragma unroll
    for (int b = 0; b < CT; ++b) acc[s][b] = (floatx4){0.f, 0.f, 0.f, 0.f};

#pragma unroll 2
  for (int cc = 0; cc < NCC; ++cc) {
    const bool odd = (cc & 1) != 0;
    if constexpr (CT == 4) wsb[cc & 1][t] = odd ? rb4 : ra4;
    else ((uint2*)wsb[cc & 1])[t] = odd ? rb2 : ra2;
    if (cc + 2 < NCC) {
      const char* np = wgp + (size_t)(cc + 2) * CHB;
      if constexpr (CT == 4) {
        if (odd) rb4 = *(const uint4*)(np + t * 16); else ra4 = *(const uint4*)(np + t * 16);
      } else {
        if (odd) rb2 = *(const uint2*)(np + t * 8); else ra2 = *(const uint2*)(np + t * 8);
      }
    }
    __syncthreads();
    const _Float16* wb = (const _Float16*)wsb[cc & 1];
    half8_t bf[CT];
#pragma unroll
    for (int b = 0; b < CT; ++b)
      bf[b] = *(const half8_t*)(wb + (b * 64 + lane) * 8);
    int kl;
    if constexpr (MIP == 64) kl = cc >> 1;
    else if constexpr (MIP == 32) kl = cc;
    else kl = 2 * cc + (q >> 1);
#pragma unroll
    for (int s = 0; s < 2; ++s) {
      _Float16 hv = h16[kl * EPB + wbase + s * 16 + l15];
      half8_t af;
      if constexpr (MIP == 64) af = xf[s][cc & 1] * hv;
      else af = xf[s][0] * hv;
#pragma unroll
      for (int b = 0; b < CT; ++b)
        acc[s][b] = __builtin_amdgcn_mfma_f32_16x16x32_f16(af, bf[b], acc[s][b], 0, 0, 0);
    }
  }

  // ---- epilogue: plain fp16 partial stores, no atomics ----
  _Float16* mp = msgp + (size_t)split * NE * MO;
#pragma unroll
  for (int s = 0; s < 2; ++s) {
    int rowb = wbase + s * 16 + q * 4;
#pragma unroll
    for (int b = 0; b < CT; ++b) {
      int n = b * 16 + l15;
#pragma unroll
      for (int r = 0; r < 4; ++r) {
        int row = rowb + r;
        int e = e0 + row;
        if (e < NE) mp[(size_t)e * MO + n] = (_Float16)acc[s][b][r];
      }
    }
  }
}

// ---------------- L1/L2 message kernel: msg9 structure with 2 chunks per barrier ----------------
// Same M-split (2 subtiles/wave), same staging path, but each barrier covers a PAIR of chunks:
// 32 MFMA/wave per barrier instead of 16, halving barrier-drain count (66->33 for L2).
// Prefetch uses 4 NAMED uint4 registers (pA0,pA1,pB0,pB1) - ternary selects fold to cndmask,
// never scratch (the R5 failure was ARRAY-indexed prefetch regs).
template <int MIP, int NCC, int KCNT>
__global__ __launch_bounds__(256, 4) void msg9p_kernel(
    const float* __restrict__ ea, const float* __restrict__ w1,
    const float* __restrict__ b1, const _Float16* __restrict__ xe,
    const int* __restrict__ src,
    const _Float16* __restrict__ w2h, _Float16* __restrict__ msgp)
{
  constexpr int EPB = 128;
  constexpr int MO = 64;
  constexpr int CT = 4;
  constexpr int CHB = 4096;               // bytes per K32 chunk
  constexpr int XV = (MIP == 64) ? 2 : 1;
  constexpr int KH = (KCNT + 1) >> 1;
  static_assert((NCC & 1) == 0, "NCC must be even for paired chunks");

  __shared__ uint4 wsb[2][2][CHB / 16];   // [buffer][chunk-in-pair][256]
  __shared__ _Float16 h16[KCNT * EPB];    // transposed: h16[kl][edge]
  __shared__ float w1s[5 * 128 + 128];

  const int t = threadIdx.x;
  const int wave = t >> 6, lane = t & 63;
  const int l15 = lane & 15, q = lane >> 4;
  const int split = blockIdx.x / NBLK;
  const int e0 = (blockIdx.x % NBLK) * EPB;
  const int c0 = NCC * split;
  const int kg0 = KCNT * split;

  // ---- W prefetch: first four chunks into NAMED registers ----
  const char* wgp = (const char*)w2h + (size_t)c0 * CHB;
  uint4 pA0 = *(const uint4*)(wgp + 0 * CHB + t * 16);
  uint4 pA1 = *(const uint4*)(wgp + 1 * CHB + t * 16);
  uint4 pB0 = *(const uint4*)(wgp + 2 * CHB + t * 16);
  uint4 pB1 = *(const uint4*)(wgp + 3 * CHB + t * 16);

  // ---- x fragments direct from global (2 M-subtiles per wave) ----
  const int wbase = wave * 32;
  half8_t xf[2][XV];
#pragma unroll
  for (int s = 0; s < 2; ++s) {
    int eg = e0 + wbase + s * 16 + l15; if (eg >= NE) eg = NE - 1;
    const _Float16* xr = xe + (size_t)src[eg] * MIP;
    xf[s][0] = *(const half8_t*)(xr + q * 8);
    if constexpr (MIP == 64)
      xf[s][XV - 1] = *(const half8_t*)(xr + 32 + q * 8);
  }

  // ---- edge attrs to regs (thread-half te owns edge e0+te); w1/b1 to LDS ----
  const int te = t & 127;
  float ear[5];
  {
    int eg = e0 + te; if (eg >= NE) eg = NE - 1;
#pragma unroll
    for (int j = 0; j < 5; ++j) ear[j] = ea[(size_t)eg * 5 + j];
  }
  for (int i = t; i < 768; i += 256) w1s[i] = (i < 640) ? w1[i] : b1[i - 640];
  __syncthreads();

  // ---- h phase: each edge's KCNT values split across thread halves ----
  {
    int kh = t >> 7;
    int klo = kh * KH;
    int khi = klo + KH; if (khi > KCNT) khi = KCNT;
    for (int kl = klo; kl < khi; ++kl) {
      int kg = kg0 + kl;
      float v;
      if (kg < 128) {
        v = w1s[640 + kg];
#pragma unroll
        for (int j = 0; j < 5; ++j) v = fmaf(ear[j], w1s[j * 128 + kg], v);
        v = fmaxf(v, 0.f);
      } else v = (kg == 128) ? 1.f : 0.f;
      h16[kl * EPB + te] = (_Float16)v;
    }
  }
  __syncthreads();

  // ---- K loop: ONE barrier per 2-chunk pair, double-buffered pair slots ----
  floatx4 acc[2][CT];
#pragma unroll
  for (int s = 0; s < 2; ++s)
#pragma unroll
    for (int b = 0; b < CT; ++b) acc[s][b] = (floatx4){0.f, 0.f, 0.f, 0.f};

#pragma unroll 2
  for (int ci = 0; ci < NCC / 2; ++ci) {
    const bool odd = (ci & 1) != 0;
    // stage pair ci into buffer ci&1 from the matching named-reg pair
    wsb[ci & 1][0][t] = odd ? pB0 : pA0;
    wsb[ci & 1][1][t] = odd ? pB1 : pA1;
    // refill the just-freed named pair 4 chunks ahead
    if (2 * ci + 4 < NCC) {
      const char* np = wgp + (size_t)(2 * ci + 4) * CHB;
      if (odd) pB0 = *(const uint4*)(np + t * 16); else pA0 = *(const uint4*)(np + t * 16);
    }
    if (2 * ci + 5 < NCC) {
      const char* np = wgp + (size_t)(2 * ci + 5) * CHB;
      if (odd) pB1 = *(const uint4*)(np + t * 16); else pA1 = *(const uint4*)(np + t * 16);
    }
    __syncthreads();
#pragma unroll
    for (int u = 0; u < 2; ++u) {
      const int cc = 2 * ci + u;
      const _Float16* wbu = (const _Float16*)wsb[ci & 1][u];
      half8_t bf[CT];
#pragma unroll
      for (int b = 0; b < CT; ++b)
        bf[b] = *(const half8_t*)(wbu + (b * 64 + lane) * 8);
      int kl;
      if constexpr (MIP == 64) kl = cc >> 1;
      else kl = cc;
#pragma unroll
      for (int s = 0; s < 2; ++s) {
        _Float16 hv = h16[kl * EPB + wbase + s * 16 + l15];
        half8_t af;
        if constexpr (MIP == 64) af = xf[s][cc & 1] * hv;
        else af = xf[s][0] * hv;
#pragma unroll
        for (int b = 0; b < CT; ++b)
          acc[s][b] = __builtin_amdgcn_mfma_f32_16x16x32_f16(af, bf[b], acc[s][b], 0, 0, 0);
      }
    }
  }

  // ---- epilogue: plain fp16 partial stores, no atomics ----
  _Float16* mp = msgp + (size_t)split * NE * MO;
#pragma unroll
  for (int s = 0; s < 2; ++s) {
    int rowb = wbase + s * 16 + q * 4;
#pragma unroll
    for (int b = 0; b < CT; ++b) {
      int n = b * 16 + l15;
#pragma unroll
      for (int r = 0; r < 4; ++r) {
        int row = rowb + r;
        int e = e0 + row;
        if (e < NE) mp[(size_t)e * MO + n] = (_Float16)acc[s][b][r];
      }
    }
  }
}

// ---- gather: per node, sum CSR-listed edge partials (+root-GEMM +bias), ELU unless FINAL ----
template <int MIN_, int XST, int MO, int FINAL>
__global__ __launch_bounds__(256) void gather_kernel(
    const _Float16* __restrict__ e16in, const float* __restrict__ root,
    const float* __restrict__ bias, const int* __restrict__ row_ptr,
    const int* __restrict__ eids, const _Float16* __restrict__ msgp,
    _Float16* __restrict__ oute, float* __restrict__ outf)
{
  constexpr int NPB = 256 / MO;
  int n = blockIdx.x * NPB + threadIdx.x / MO;
  int o = threadIdx.x % MO;
  if (n >= NN) return;
  float a = bias[o];
#pragma unroll
  for (int i = 0; i < MIN_; ++i)
    a = fmaf((float)e16in[(size_t)n * XST + i], root[i * MO + o], a);
  int r0 = row_ptr[n], r1 = row_ptr[n + 1];
  for (int j = r0; j < r1; ++j) {
    int e = eids[j];
#pragma unroll
    for (int s = 0; s < NSPLIT; ++s)
      a += (float)msgp[((size_t)s * NE + e) * MO + o];
  }
  if constexpr (FINAL) {
    outf[(size_t)n * MO + o] = a;
  } else {
    float v = a > 0.f ? a : (expf(a) - 1.f);
    oute[(size_t)n * MO + o] = (_Float16)v;
  }
}

// ---- pooling (segment mean over sorted batch, fused ELU) + 3-layer FC head ----
__global__ __launch_bounds__(64) void pool_fc_kernel(
    const float* __restrict__ xn2, const int* __restrict__ batch,
    const float* __restrict__ f1w, const float* __restrict__ f1b,
    const float* __restrict__ f2w, const float* __restrict__ f2b,
    const float* __restrict__ f3w, const float* __restrict__ f3b,
    float* __restrict__ out)
{
  __shared__ float xg[64]; __shared__ float a1[32]; __shared__ float a2[16];
  int g = blockIdx.x, t = threadIdx.x;
  int lo = 0, hi = NN;
  while (lo < hi) { int m = (lo + hi) >> 1; if (batch[m] < g) lo = m + 1; else hi = m; }
  int start = lo; hi = NN;
  while (lo < hi) { int m = (lo + hi) >> 1; if (batch[m] <= g) lo = m + 1; else hi = m; }
  int end = lo;
  float acc = 0.f;
  for (int n = start; n < end; ++n) {
    float v = xn2[(size_t)n * 64 + t];
    acc += v > 0.f ? v : (expf(v) - 1.f);
  }
  float c = (end > start) ? (float)(end - start) : 1.f;
  xg[t] = acc / c;
  __syncthreads();
  if (t < 32) {
    float a = f1b[t];
    for (int i = 0; i < 64; ++i) a = fmaf(xg[i], f1w[i * 32 + t], a);
    a1[t] = a > 0.f ? a : (expf(a) - 1.f);
  }
  __syncthreads();
  if (t < 16) {
    float a = f2b[t];
    for (int i = 0; i < 32; ++i) a = fmaf(a1[i], f2w[i * 16 + t], a);
    a2[t] = a > 0.f ? a : (expf(a) - 1.f);
  }
  __syncthreads();
  if (t == 0) {
    float a = f3b[0];
    for (int i = 0; i < 16; ++i) a = fmaf(a2[i], f3w[i], a);
    out[g] = a;
  }
}

extern "C" void kernel_launch(void* const* d_in, const int* in_sizes, int n_in,
                              void* d_out, int out_size, void* d_ws, size_t ws_size,
                              hipStream_t stream)
{
  const float* x_in  = (const float*)d_in[0];
  const int*   ei    = (const int*)d_in[1];
  const float* ea    = (const float*)d_in[2];
  const int*   batch = (const int*)d_in[3];
  const float* W1[3] = {(const float*)d_in[4],  (const float*)d_in[10], (const float*)d_in[16]};
  const float* B1[3] = {(const float*)d_in[5],  (const float*)d_in[11], (const float*)d_in[17]};
  const float* W2[3] = {(const float*)d_in[6],  (const float*)d_in[12], (const float*)d_in[18]};
  const float* B2[3] = {(const float*)d_in[7],  (const float*)d_in[13], (const float*)d_in[19]};
  const float* RT[3] = {(const float*)d_in[8],  (const float*)d_in[14], (const float*)d_in[20]};
  const float* BS[3] = {(const float*)d_in[9],  (const float*)d_in[15], (const float*)d_in[21]};
  const float* f1w = (const float*)d_in[22]; const float* f1b = (const float*)d_in[23];
  const float* f2w = (const float*)d_in[24]; const float* f2b = (const float*)d_in[25];
  const float* f3w = (const float*)d_in[26]; const float* f3b = (const float*)d_in[27];

  char* ws = (char*)d_ws;
  size_t off = 0;
  auto alloc = [&](size_t bytes) { void* p = ws + off; off += (bytes + 255) & ~(size_t)255; return p; };
  float*    xn2   = (float*)alloc((size_t)NN * 64 * 4);
  _Float16* e16_0 = (_Float16*)alloc((size_t)NN * 16 * 2);
  _Float16* e16_1 = (_Float16*)alloc((size_t)NN * 32 * 2);
  _Float16* e16_2 = (_Float16*)alloc((size_t)NN * 64 * 2);
  _Float16* w2h0  = (_Float16*)alloc((size_t)68 * 2048);
  _Float16* w2h1  = (_Float16*)alloc((size_t)136 * 4096);  // padded to 34 chunks/split
  _Float16* w2h2  = (_Float16*)alloc((size_t)264 * 4096);
  _Float16* msgp  = (_Float16*)alloc((size_t)NSPLIT * NE * 64 * 2);
  int*      deg     = (int*)alloc((size_t)NN * 4);
  int*      row_ptr = (int*)alloc((size_t)(NN + 1) * 4);
  int*      cursor  = (int*)alloc((size_t)NN * 4);
  int*      eids    = (int*)alloc((size_t)NE * 4);

  const int* srcp = ei;
  const int* dstp = ei + NE;

  prep_fused_kernel<<<1684 + (NN + 255) / 256, 256, 0, stream>>>(
      x_in, e16_0, W2[0], B2[0], w2h0, W2[1], B2[1], w2h1, W2[2], B2[2], w2h2, deg);
  deg_kernel<<<(NE + 255) / 256, 256, 0, stream>>>(dstp, deg);
  scan_kernel<<<1, 1024, 0, stream>>>(deg, row_ptr, cursor);
  fill_kernel<<<(NE + 255) / 256, 256, 0, stream>>>(dstp, cursor, eids);

  // ---- layer 0: R6 msg9, 17 chunks/split, KCNT=34 ----
  msg9_kernel<16, 32, 17, 34><<<NBLK * NSPLIT, 256, 0, stream>>>(
      ea, W1[0], B1[0], e16_0, srcp, w2h0, msgp);
  gather_kernel<13, 16, 32, 0><<<(NN + 7) / 8, 256, 0, stream>>>(
      e16_0, RT[0], BS[0], row_ptr, eids, msgp, e16_1, xn2);

  // ---- layer 1: paired-chunk msg9p, 34 chunks/split (padded), KCNT=34 ----
  msg9p_kernel<32, 34, 34><<<NBLK * NSPLIT, 256, 0, stream>>>(
      ea, W1[1], B1[1], e16_1, srcp, w2h1, msgp);
  gather_kernel<32, 32, 64, 0><<<(NN + 3) / 4, 256, 0, stream>>>(
      e16_1, RT[1], BS[1], row_ptr, eids, msgp, e16_2, xn2);

  // ---- layer 2: paired-chunk msg9p, 66 chunks/split, KCNT=33 ----
  msg9p_kernel<64, 66, 33><<<NBLK * NSPLIT, 256, 0, stream>>>(
      ea, W1[2], B1[2], e16_2, srcp, w2h2, msgp);
  gather_kernel<64, 64, 64, 1><<<(NN + 3) / 4, 256, 0, stream>>>(
      e16_2, RT[2], BS[2], row_ptr, eids, msgp, e16_2, xn2);

  pool_fc_kernel<<<NG, 64, 0, stream>>>(xn2, batch, f1w, f1b, f2w, f2b, f3w, f3b, (float*)d_out);
}

// Round 11
// 286.226 us; speedup vs baseline: 1.0874x; 1.0347x over previous
//
#include <hip/hip_runtime.h>
#include <stdint.h>
#include <math.h>

typedef _Float16 half8_t __attribute__((ext_vector_type(8)));
typedef float floatx4 __attribute__((ext_vector_type(4)));

#define NN 20000
#define NE 40000
#define NG 1000
#define NBLK 313      // ceil(NE/128)  -- 128 edges per block
#define NSPLIT 4

// ---- fused prep: [0,1250) x0->e16 pad ; [1250,1680) w2 -> B-frag images ; [1680..) deg=0 ----
// Chunk counts (NSPLIT=4): L0 = 68 (4x17), L1 = 132 (4x33), L2 = 264 (4x66).
__global__ __launch_bounds__(256) void prep_fused_kernel(
    const float* __restrict__ x, _Float16* __restrict__ e16,
    const float* __restrict__ w2a, const float* __restrict__ b2a, _Float16* __restrict__ oa,
    const float* __restrict__ w2b, const float* __restrict__ b2b, _Float16* __restrict__ ob,
    const float* __restrict__ w2c, const float* __restrict__ b2c, _Float16* __restrict__ oc,
    int* __restrict__ deg)
{
  if (blockIdx.x < 1250) {
    int idx = blockIdx.x * 256 + threadIdx.x;   // over NN*16
    int n = idx >> 4, i = idx & 15;
    e16[idx] = (i < 13) ? (_Float16)x[(size_t)n * 13 + i] : (_Float16)0.f;
    return;
  }
  if (blockIdx.x >= 1680) {
    int n = (blockIdx.x - 1680) * 256 + threadIdx.x;
    if (n < NN) deg[n] = 0;
    return;
  }
  const int TOT0 = 68 * 2 * 64, TOT1 = 132 * 4 * 64, TOT2 = 264 * 4 * 64;
  int idx = (blockIdx.x - 1250) * 256 + threadIdx.x;
  const float *w2, *b2; _Float16* op; int mi, mo, mpsh, CT;
  if (idx < TOT0) { w2 = w2a; b2 = b2a; op = oa; mi = 13; mo = 32; mpsh = 4; CT = 2; }
  else if (idx < TOT0 + TOT1) { idx -= TOT0; w2 = w2b; b2 = b2b; op = ob; mi = 32; mo = 64; mpsh = 5; CT = 4; }
  else if (idx < TOT0 + TOT1 + TOT2) { idx -= TOT0 + TOT1; w2 = w2c; b2 = b2c; op = oc; mi = 64; mo = 64; mpsh = 6; CT = 4; }
  else return;
  int l = idx & 63;
  int ct = (idx >> 6) % CT;
  int c = idx / (64 * CT);
  int q = l >> 4;
  int n = ct * 16 + (l & 15);
  int mask = (1 << mpsh) - 1;
  half8_t v;
#pragma unroll
  for (int j = 0; j < 8; ++j) {
    int r = c * 32 + q * 8 + j;
    int k = r >> mpsh, i = r & mask;
    float f = 0.f;
    if (i < mi) {
      if (k < 128) f = w2[(size_t)(k * mi + i) * mo + n];
      else if (k == 128) f = b2[(size_t)i * mo + n];
    }
    v[j] = (_Float16)f;
  }
  *(half8_t*)(op + (size_t)idx * 8) = v;
}

// ---- CSR build: histogram, parallel scan, fill ----
__global__ __launch_bounds__(256) void deg_kernel(const int* __restrict__ dst, int* __restrict__ deg) {
  int e = blockIdx.x * 256 + threadIdx.x;
  if (e < NE) atomicAdd(&deg[dst[e]], 1);
}

__global__ __launch_bounds__(1024) void scan_kernel(
    const int* __restrict__ deg, int* __restrict__ row_ptr, int* __restrict__ cursor)
{
  constexpr int CH = 20;                 // 1024*20 = 20480 >= NN+1
  __shared__ int wsum[16];
  int t = threadIdx.x;
  int lane = t & 63, w = t >> 6;
  int base = t * CH;
  int local[CH];
#pragma unroll
  for (int i = 0; i < CH; ++i) {
    int n = base + i;
    local[i] = (n < NN) ? deg[n] : 0;
  }
  int s = 0;
#pragma unroll
  for (int i = 0; i < CH; ++i) s += local[i];
  int sc = s;
#pragma unroll
  for (int d = 1; d < 64; d <<= 1) {
    int v = __shfl_up(sc, d, 64);
    if (lane >= d) sc += v;
  }
  if (lane == 63) wsum[w] = sc;
  __syncthreads();
  if (w == 0 && lane < 16) {
    int v = wsum[lane];
    int scc = v;
#pragma unroll
    for (int d = 1; d < 16; d <<= 1) {
      int u = __shfl_up(scc, d, 64);
      if (lane >= d) scc += u;
    }
    wsum[lane] = scc - v;                // exclusive wave prefix
  }
  __syncthreads();
  int run = wsum[w] + (sc - s);          // exclusive prefix for this thread
#pragma unroll
  for (int i = 0; i < CH; ++i) {
    int n = base + i;
    if (n < NN) { row_ptr[n] = run; cursor[n] = run; run += local[i]; }
    else if (n == NN) row_ptr[NN] = run;
  }
}

__global__ __launch_bounds__(256) void fill_kernel(
    const int* __restrict__ dst, int* __restrict__ cursor, int* __restrict__ eids)
{
  int e = blockIdx.x * 256 + threadIdx.x;
  if (e < NE) { int p = atomicAdd(&cursor[dst[e]], 1); eids[p] = e; }
}

// ---------------- L0/L1 message kernel: R6 structure (proven best), LDS W staging ----------------
// msgp layout: [e][split][MO] (interleaved) so gather reads one contiguous block per edge.
template <int MIP, int MO, int NCC, int KCNT>
__global__ __launch_bounds__(256, 4) void msg9_kernel(
    const float* __restrict__ ea, const float* __restrict__ w1,
    const float* __restrict__ b1, const _Float16* __restrict__ xe,
    const int* __restrict__ src,
    const _Float16* __restrict__ w2h, _Float16* __restrict__ msgp)
{
  constexpr int EPB = 128;                // edges per block
  constexpr int CT = MO / 16;
  constexpr int CHB = CT * 1024;          // BYTES per K32-chunk of W image
  constexpr int XV = (MIP == 64) ? 2 : 1;
  constexpr int KH = (KCNT + 1) >> 1;     // h k-values per thread-half

  __shared__ uint4 wsb[2][CHB / 16];
  __shared__ _Float16 h16[KCNT * EPB];    // transposed: h16[kl][edge]
  __shared__ float w1s[5 * 128 + 128];

  const int t = threadIdx.x;
  const int wave = t >> 6, lane = t & 63;
  const int l15 = lane & 15, q = lane >> 4;
  const int split = blockIdx.x / NBLK;
  const int e0 = (blockIdx.x % NBLK) * EPB;
  const int c0 = NCC * split;
  const int kg0 = KCNT * split;

  // ---- W prefetch: first two chunks into named registers ----
  const char* wgp = (const char*)w2h + (size_t)c0 * CHB;
  uint4 ra4, rb4; uint2 ra2, rb2;
  if constexpr (CT == 4) {
    ra4 = *(const uint4*)(wgp + t * 16);
    rb4 = *(const uint4*)(wgp + CHB + t * 16);
  } else {
    ra2 = *(const uint2*)(wgp + t * 8);
    rb2 = *(const uint2*)(wgp + CHB + t * 8);
  }

  // ---- x fragments direct from global (2 M-subtiles per wave) ----
  const int wbase = wave * 32;
  half8_t xf[2][XV];
#pragma unroll
  for (int s = 0; s < 2; ++s) {
    int eg = e0 + wbase + s * 16 + l15; if (eg >= NE) eg = NE - 1;
    const _Float16* xr = xe + (size_t)src[eg] * MIP;
    int i0 = (MIP == 16) ? (q & 1) * 8 : q * 8;
    xf[s][0] = *(const half8_t*)(xr + i0);
    if constexpr (MIP == 64)
      xf[s][XV - 1] = *(const half8_t*)(xr + 32 + q * 8);
  }

  // ---- edge attrs to regs (thread-half te owns edge e0+te); w1/b1 to LDS ----
  const int te = t & 127;
  float ear[5];
  {
    int eg = e0 + te; if (eg >= NE) eg = NE - 1;
#pragma unroll
    for (int j = 0; j < 5; ++j) ear[j] = ea[(size_t)eg * 5 + j];
  }
  for (int i = t; i < 768; i += 256) w1s[i] = (i < 640) ? w1[i] : b1[i - 640];
  __syncthreads();

  // ---- h phase: each edge's KCNT values split across thread halves ----
  {
    int kh = t >> 7;
    int klo = kh * KH;
    int khi = klo + KH; if (khi > KCNT) khi = KCNT;
    for (int kl = klo; kl < khi; ++kl) {
      int kg = kg0 + kl;
      float v;
      if (kg < 128) {
        v = w1s[640 + kg];
#pragma unroll
        for (int j = 0; j < 5; ++j) v = fmaf(ear[j], w1s[j * 128 + kg], v);
        v = fmaxf(v, 0.f);
      } else v = (kg == 128) ? 1.f : 0.f;
      h16[kl * EPB + te] = (_Float16)v;
    }
  }
  __syncthreads();

  // ---- K loop: 1 barrier/chunk, LDS double-buffer, 2-deep register prefetch ----
  floatx4 acc[2][CT];
#pragma unroll
  for (int s = 0; s < 2; ++s)
#pragma unroll
    for (int b = 0; b < CT; ++b) acc[s][b] = (floatx4){0.f, 0.f, 0.f, 0.f};

#pragma unroll 2
  for (int cc = 0; cc < NCC; ++cc) {
    const bool odd = (cc & 1) != 0;
    if constexpr (CT == 4) wsb[cc & 1][t] = odd ? rb4 : ra4;
    else ((uint2*)wsb[cc & 1])[t] = odd ? rb2 : ra2;
    if (cc + 2 < NCC) {
      const char* np = wgp + (size_t)(cc + 2) * CHB;
      if constexpr (CT == 4) {
        if (odd) rb4 = *(const uint4*)(np + t * 16); else ra4 = *(const uint4*)(np + t * 16);
      } else {
        if (odd) rb2 = *(const uint2*)(np + t * 8); else ra2 = *(const uint2*)(np + t * 8);
      }
    }
    __syncthreads();
    const _Float16* wb = (const _Float16*)wsb[cc & 1];
    half8_t bf[CT];
#pragma unroll
    for (int b = 0; b < CT; ++b)
      bf[b] = *(const half8_t*)(wb + (b * 64 + lane) * 8);
    int kl;
    if constexpr (MIP == 64) kl = cc >> 1;
    else if constexpr (MIP == 32) kl = cc;
    else kl = 2 * cc + (q >> 1);
#pragma unroll
    for (int s = 0; s < 2; ++s) {
      _Float16 hv = h16[kl * EPB + wbase + s * 16 + l15];
      half8_t af;
      if constexpr (MIP == 64) af = xf[s][cc & 1] * hv;
      else af = xf[s][0] * hv;
#pragma unroll
      for (int b = 0; b < CT; ++b)
        acc[s][b] = __builtin_amdgcn_mfma_f32_16x16x32_f16(af, bf[b], acc[s][b], 0, 0, 0);
    }
  }

  // ---- epilogue: interleaved partial stores msgp[e][split][MO], no atomics ----
#pragma unroll
  for (int s = 0; s < 2; ++s) {
    int rowb = wbase + s * 16 + q * 4;
#pragma unroll
    for (int b = 0; b < CT; ++b) {
      int n = b * 16 + l15;
#pragma unroll
      for (int r = 0; r < 4; ++r) {
        int row = rowb + r;
        int e = e0 + row;
        if (e < NE) msgp[((size_t)e * NSPLIT + split) * MO + n] = (_Float16)acc[s][b][r];
      }
    }
  }
}

// ---------------- L2 message kernel: msg9 structure with 2 chunks per barrier ----------------
// 4 NAMED uint4 prefetch regs (ternaries fold to cndmask, no scratch). 32 MFMA/wave/barrier.
template <int MIP, int NCC, int KCNT>
__global__ __launch_bounds__(256, 4) void msg9p_kernel(
    const float* __restrict__ ea, const float* __restrict__ w1,
    const float* __restrict__ b1, const _Float16* __restrict__ xe,
    const int* __restrict__ src,
    const _Float16* __restrict__ w2h, _Float16* __restrict__ msgp)
{
  constexpr int EPB = 128;
  constexpr int MO = 64;
  constexpr int CT = 4;
  constexpr int CHB = 4096;               // bytes per K32 chunk
  constexpr int XV = (MIP == 64) ? 2 : 1;
  constexpr int KH = (KCNT + 1) >> 1;
  static_assert((NCC & 1) == 0, "NCC must be even for paired chunks");

  __shared__ uint4 wsb[2][2][CHB / 16];   // [buffer][chunk-in-pair][256]
  __shared__ _Float16 h16[KCNT * EPB];    // transposed: h16[kl][edge]
  __shared__ float w1s[5 * 128 + 128];

  const int t = threadIdx.x;
  const int wave = t >> 6, lane = t & 63;
  const int l15 = lane & 15, q = lane >> 4;
  const int split = blockIdx.x / NBLK;
  const int e0 = (blockIdx.x % NBLK) * EPB;
  const int c0 = NCC * split;
  const int kg0 = KCNT * split;

  // ---- W prefetch: first four chunks into NAMED registers ----
  const char* wgp = (const char*)w2h + (size_t)c0 * CHB;
  uint4 pA0 = *(const uint4*)(wgp + 0 * CHB + t * 16);
  uint4 pA1 = *(const uint4*)(wgp + 1 * CHB + t * 16);
  uint4 pB0 = *(const uint4*)(wgp + 2 * CHB + t * 16);
  uint4 pB1 = *(const uint4*)(wgp + 3 * CHB + t * 16);

  // ---- x fragments direct from global (2 M-subtiles per wave) ----
  const int wbase = wave * 32;
  half8_t xf[2][XV];
#pragma unroll
  for (int s = 0; s < 2; ++s) {
    int eg = e0 + wbase + s * 16 + l15; if (eg >= NE) eg = NE - 1;
    const _Float16* xr = xe + (size_t)src[eg] * MIP;
    xf[s][0] = *(const half8_t*)(xr + q * 8);
    if constexpr (MIP == 64)
      xf[s][XV - 1] = *(const half8_t*)(xr + 32 + q * 8);
  }

  // ---- edge attrs to regs (thread-half te owns edge e0+te); w1/b1 to LDS ----
  const int te = t & 127;
  float ear[5];
  {
    int eg = e0 + te; if (eg >= NE) eg = NE - 1;
#pragma unroll
    for (int j = 0; j < 5; ++j) ear[j] = ea[(size_t)eg * 5 + j];
  }
  for (int i = t; i < 768; i += 256) w1s[i] = (i < 640) ? w1[i] : b1[i - 640];
  __syncthreads();

  // ---- h phase: each edge's KCNT values split across thread halves ----
  {
    int kh = t >> 7;
    int klo = kh * KH;
    int khi = klo + KH; if (khi > KCNT) khi = KCNT;
    for (int kl = klo; kl < khi; ++kl) {
      int kg = kg0 + kl;
      float v;
      if (kg < 128) {
        v = w1s[640 + kg];
#pragma unroll
        for (int j = 0; j < 5; ++j) v = fmaf(ear[j], w1s[j * 128 + kg], v);
        v = fmaxf(v, 0.f);
      } else v = (kg == 128) ? 1.f : 0.f;
      h16[kl * EPB + te] = (_Float16)v;
    }
  }
  __syncthreads();

  // ---- K loop: ONE barrier per 2-chunk pair, double-buffered pair slots ----
  floatx4 acc[2][CT];
#pragma unroll
  for (int s = 0; s < 2; ++s)
#pragma unroll
    for (int b = 0; b < CT; ++b) acc[s][b] = (floatx4){0.f, 0.f, 0.f, 0.f};

#pragma unroll 2
  for (int ci = 0; ci < NCC / 2; ++ci) {
    const bool odd = (ci & 1) != 0;
    wsb[ci & 1][0][t] = odd ? pB0 : pA0;
    wsb[ci & 1][1][t] = odd ? pB1 : pA1;
    if (2 * ci + 4 < NCC) {
      const char* np = wgp + (size_t)(2 * ci + 4) * CHB;
      if (odd) pB0 = *(const uint4*)(np + t * 16); else pA0 = *(const uint4*)(np + t * 16);
    }
    if (2 * ci + 5 < NCC) {
      const char* np = wgp + (size_t)(2 * ci + 5) * CHB;
      if (odd) pB1 = *(const uint4*)(np + t * 16); else pA1 = *(const uint4*)(np + t * 16);
    }
    __syncthreads();
#pragma unroll
    for (int u = 0; u < 2; ++u) {
      const int cc = 2 * ci + u;
      const _Float16* wbu = (const _Float16*)wsb[ci & 1][u];
      half8_t bf[CT];
#pragma unroll
      for (int b = 0; b < CT; ++b)
        bf[b] = *(const half8_t*)(wbu + (b * 64 + lane) * 8);
      int kl;
      if constexpr (MIP == 64) kl = cc >> 1;
      else kl = cc;
#pragma unroll
      for (int s = 0; s < 2; ++s) {
        _Float16 hv = h16[kl * EPB + wbase + s * 16 + l15];
        half8_t af;
        if constexpr (MIP == 64) af = xf[s][cc & 1] * hv;
        else af = xf[s][0] * hv;
#pragma unroll
        for (int b = 0; b < CT; ++b)
          acc[s][b] = __builtin_amdgcn_mfma_f32_16x16x32_f16(af, bf[b], acc[s][b], 0, 0, 0);
      }
    }
  }

  // ---- epilogue: interleaved partial stores msgp[e][split][64], no atomics ----
#pragma unroll
  for (int s = 0; s < 2; ++s) {
    int rowb = wbase + s * 16 + q * 4;
#pragma unroll
    for (int b = 0; b < CT; ++b) {
      int n = b * 16 + l15;
#pragma unroll
      for (int r = 0; r < 4; ++r) {
        int row = rowb + r;
        int e = e0 + row;
        if (e < NE) msgp[((size_t)e * NSPLIT + split) * MO + n] = (_Float16)acc[s][b][r];
      }
    }
  }
}

// ---- gather: per node, sum CSR-listed edge partials (+root-GEMM +bias), ELU unless FINAL ----
// msgp interleaved [e][split][MO]: one contiguous NSPLIT*MO block per edge.
template <int MIN_, int XST, int MO, int FINAL>
__global__ __launch_bounds__(256) void gather_kernel(
    const _Float16* __restrict__ e16in, const float* __restrict__ root,
    const float* __restrict__ bias, const int* __restrict__ row_ptr,
    const int* __restrict__ eids, const _Float16* __restrict__ msgp,
    _Float16* __restrict__ oute, float* __restrict__ outf)
{
  constexpr int NPB = 256 / MO;
  int n = blockIdx.x * NPB + threadIdx.x / MO;
  int o = threadIdx.x % MO;
  if (n >= NN) return;
  float a = bias[o];
#pragma unroll
  for (int i = 0; i < MIN_; ++i)
    a = fmaf((float)e16in[(size_t)n * XST + i], root[i * MO + o], a);
  int r0 = row_ptr[n], r1 = row_ptr[n + 1];
  for (int j = r0; j < r1; ++j) {
    int e = eids[j];
    const _Float16* ep = msgp + (size_t)e * NSPLIT * MO + o;
#pragma unroll
    for (int s = 0; s < NSPLIT; ++s)
      a += (float)ep[s * MO];
  }
  if constexpr (FINAL) {
    outf[(size_t)n * MO + o] = a;
  } else {
    float v = a > 0.f ? a : (expf(a) - 1.f);
    oute[(size_t)n * MO + o] = (_Float16)v;
  }
}

// ---- pooling (segment mean over sorted batch, fused ELU) + 3-layer FC head ----
__global__ __launch_bounds__(64) void pool_fc_kernel(
    const float* __restrict__ xn2, const int* __restrict__ batch,
    const float* __restrict__ f1w, const float* __restrict__ f1b,
    const float* __restrict__ f2w, const float* __restrict__ f2b,
    const float* __restrict__ f3w, const float* __restrict__ f3b,
    float* __restrict__ out)
{
  __shared__ float xg[64]; __shared__ float a1[32]; __shared__ float a2[16];
  int g = blockIdx.x, t = threadIdx.x;
  int lo = 0, hi = NN;
  while (lo < hi) { int m = (lo + hi) >> 1; if (batch[m] < g) lo = m + 1; else hi = m; }
  int start = lo; hi = NN;
  while (lo < hi) { int m = (lo + hi) >> 1; if (batch[m] <= g) lo = m + 1; else hi = m; }
  int end = lo;
  float acc = 0.f;
  for (int n = start; n < end; ++n) {
    float v = xn2[(size_t)n * 64 + t];
    acc += v > 0.f ? v : (expf(v) - 1.f);
  }
  float c = (end > start) ? (float)(end - start) : 1.f;
  xg[t] = acc / c;
  __syncthreads();
  if (t < 32) {
    float a = f1b[t];
    for (int i = 0; i < 64; ++i) a = fmaf(xg[i], f1w[i * 32 + t], a);
    a1[t] = a > 0.f ? a : (expf(a) - 1.f);
  }
  __syncthreads();
  if (t < 16) {
    float a = f2b[t];
    for (int i = 0; i < 32; ++i) a = fmaf(a1[i], f2w[i * 16 + t], a);
    a2[t] = a > 0.f ? a : (expf(a) - 1.f);
  }
  __syncthreads();
  if (t == 0) {
    float a = f3b[0];
    for (int i = 0; i < 16; ++i) a = fmaf(a2[i], f3w[i], a);
    out[g] = a;
  }
}

extern "C" void kernel_launch(void* const* d_in, const int* in_sizes, int n_in,
                              void* d_out, int out_size, void* d_ws, size_t ws_size,
                              hipStream_t stream)
{
  const float* x_in  = (const float*)d_in[0];
  const int*   ei    = (const int*)d_in[1];
  const float* ea    = (const float*)d_in[2];
  const int*   batch = (const int*)d_in[3];
  const float* W1[3] = {(const float*)d_in[4],  (const float*)d_in[10], (const float*)d_in[16]};
  const float* B1[3] = {(const float*)d_in[5],  (const float*)d_in[11], (const float*)d_in[17]};
  const float* W2[3] = {(const float*)d_in[6],  (const float*)d_in[12], (const float*)d_in[18]};
  const float* B2[3] = {(const float*)d_in[7],  (const float*)d_in[13], (const float*)d_in[19]};
  const float* RT[3] = {(const float*)d_in[8],  (const float*)d_in[14], (const float*)d_in[20]};
  const float* BS[3] = {(const float*)d_in[9],  (const float*)d_in[15], (const float*)d_in[21]};
  const float* f1w = (const float*)d_in[22]; const float* f1b = (const float*)d_in[23];
  const float* f2w = (const float*)d_in[24]; const float* f2b = (const float*)d_in[25];
  const float* f3w = (const float*)d_in[26]; const float* f3b = (const float*)d_in[27];

  char* ws = (char*)d_ws;
  size_t off = 0;
  auto alloc = [&](size_t bytes) { void* p = ws + off; off += (bytes + 255) & ~(size_t)255; return p; };
  float*    xn2   = (float*)alloc((size_t)NN * 64 * 4);
  _Float16* e16_0 = (_Float16*)alloc((size_t)NN * 16 * 2);
  _Float16* e16_1 = (_Float16*)alloc((size_t)NN * 32 * 2);
  _Float16* e16_2 = (_Float16*)alloc((size_t)NN * 64 * 2);
  _Float16* w2h0  = (_Float16*)alloc((size_t)68 * 2048);
  _Float16* w2h1  = (_Float16*)alloc((size_t)132 * 4096);
  _Float16* w2h2  = (_Float16*)alloc((size_t)264 * 4096);
  _Float16* msgp  = (_Float16*)alloc((size_t)NSPLIT * NE * 64 * 2);
  int*      deg     = (int*)alloc((size_t)NN * 4);
  int*      row_ptr = (int*)alloc((size_t)(NN + 1) * 4);
  int*      cursor  = (int*)alloc((size_t)NN * 4);
  int*      eids    = (int*)alloc((size_t)NE * 4);

  const int* srcp = ei;
  const int* dstp = ei + NE;

  prep_fused_kernel<<<1680 + (NN + 255) / 256, 256, 0, stream>>>(
      x_in, e16_0, W2[0], B2[0], w2h0, W2[1], B2[1], w2h1, W2[2], B2[2], w2h2, deg);
  deg_kernel<<<(NE + 255) / 256, 256, 0, stream>>>(dstp, deg);
  scan_kernel<<<1, 1024, 0, stream>>>(deg, row_ptr, cursor);
  fill_kernel<<<(NE + 255) / 256, 256, 0, stream>>>(dstp, cursor, eids);

  // ---- layer 0: msg9, 17 chunks/split, KCNT=34 ----
  msg9_kernel<16, 32, 17, 34><<<NBLK * NSPLIT, 256, 0, stream>>>(
      ea, W1[0], B1[0], e16_0, srcp, w2h0, msgp);
  gather_kernel<13, 16, 32, 0><<<(NN + 7) / 8, 256, 0, stream>>>(
      e16_0, RT[0], BS[0], row_ptr, eids, msgp, e16_1, xn2);

  // ---- layer 1: msg9, 33 chunks/split, KCNT=33 ----
  msg9_kernel<32, 64, 33, 33><<<NBLK * NSPLIT, 256, 0, stream>>>(
      ea, W1[1], B1[1], e16_1, srcp, w2h1, msgp);
  gather_kernel<32, 32, 64, 0><<<(NN + 3) / 4, 256, 0, stream>>>(
      e16_1, RT[1], BS[1], row_ptr, eids, msgp, e16_2, xn2);

  // ---- layer 2: paired-chunk msg9p, 66 chunks/split, KCNT=33 ----
  msg9p_kernel<64, 66, 33><<<NBLK * NSPLIT, 256, 0, stream>>>(
      ea, W1[2], B1[2], e16_2, srcp, w2h2, msgp);
  gather_kernel<64, 64, 64, 1><<<(NN + 3) / 4, 256, 0, stream>>>(
      e16_2, RT[2], BS[2], row_ptr, eids, msgp, e16_2, xn2);

  pool_fc_kernel<<<NG, 64, 0, stream>>>(xn2, batch, f1w, f1b, f2w, f2b, f3w, f3b, (float*)d_out);
}

// Round 12
// 282.444 us; speedup vs baseline: 1.1019x; 1.0134x over previous
//
#include <hip/hip_runtime.h>
#include <stdint.h>
#include <math.h>

typedef _Float16 half8_t __attribute__((ext_vector_type(8)));
typedef float floatx4 __attribute__((ext_vector_type(4)));

#define NN 20000
#define NE 40000
#define NG 1000
#define NBLK 313      // ceil(NE/128)  -- 128 edges per block
#define NSPLIT 4

// ---------------- fused prep + CSR(deg+scan): one kernel, 1024 threads ----------------
// block 0           : degree histogram in LDS + parallel scan -> row_ptr, cursor
// blocks 1..313     : x -> e16 pad (NN*16 = 320000 elems)
// blocks 314..421   : w2 -> B-frag images (110080 half8 elems: L0 68, L1 132, L2 264 chunks)
__global__ __launch_bounds__(1024) void prep_csr_kernel(
    const float* __restrict__ x, _Float16* __restrict__ e16,
    const float* __restrict__ w2a, const float* __restrict__ b2a, _Float16* __restrict__ oa,
    const float* __restrict__ w2b, const float* __restrict__ b2b, _Float16* __restrict__ ob,
    const float* __restrict__ w2c, const float* __restrict__ b2c, _Float16* __restrict__ oc,
    const int* __restrict__ dst, int* __restrict__ row_ptr, int* __restrict__ cursor)
{
  __shared__ int sdeg[20480];            // 80 KB; used by block 0 only
  __shared__ int wsum[16];

  if (blockIdx.x == 0) {
    constexpr int CH = 20;               // 1024*20 = 20480 >= NN+1
    int t = threadIdx.x;
    int lane = t & 63, w = t >> 6;
    for (int i = t; i < 20480; i += 1024) sdeg[i] = 0;
    __syncthreads();
    for (int e = t; e < NE; e += 1024) atomicAdd(&sdeg[dst[e]], 1);
    __syncthreads();
    int base = t * CH;
    int local[CH];
#pragma unroll
    for (int i = 0; i < CH; ++i) local[i] = sdeg[base + i];
    int s = 0;
#pragma unroll
    for (int i = 0; i < CH; ++i) s += local[i];
    int sc = s;
#pragma unroll
    for (int d = 1; d < 64; d <<= 1) {
      int v = __shfl_up(sc, d, 64);
      if (lane >= d) sc += v;
    }
    if (lane == 63) wsum[w] = sc;
    __syncthreads();
    if (w == 0 && lane < 16) {
      int v = wsum[lane];
      int scc = v;
#pragma unroll
      for (int d = 1; d < 16; d <<= 1) {
        int u = __shfl_up(scc, d, 64);
        if (lane >= d) scc += u;
      }
      wsum[lane] = scc - v;              // exclusive wave prefix
    }
    __syncthreads();
    int run = wsum[w] + (sc - s);        // exclusive prefix for this thread
#pragma unroll
    for (int i = 0; i < CH; ++i) {
      int n = base + i;
      if (n < NN) { row_ptr[n] = run; cursor[n] = run; run += local[i]; }
      else if (n == NN) row_ptr[NN] = run;
    }
    return;
  }

  if (blockIdx.x <= 313) {
    int idx = (blockIdx.x - 1) * 1024 + threadIdx.x;   // over NN*16
    if (idx >= NN * 16) return;
    int n = idx >> 4, i = idx & 15;
    e16[idx] = (i < 13) ? (_Float16)x[(size_t)n * 13 + i] : (_Float16)0.f;
    return;
  }

  const int TOT0 = 68 * 2 * 64, TOT1 = 132 * 4 * 64, TOT2 = 264 * 4 * 64;
  int idx = (blockIdx.x - 314) * 1024 + threadIdx.x;
  const float *w2, *b2; _Float16* op; int mi, mo, mpsh, CT;
  if (idx < TOT0) { w2 = w2a; b2 = b2a; op = oa; mi = 13; mo = 32; mpsh = 4; CT = 2; }
  else if (idx < TOT0 + TOT1) { idx -= TOT0; w2 = w2b; b2 = b2b; op = ob; mi = 32; mo = 64; mpsh = 5; CT = 4; }
  else if (idx < TOT0 + TOT1 + TOT2) { idx -= TOT0 + TOT1; w2 = w2c; b2 = b2c; op = oc; mi = 64; mo = 64; mpsh = 6; CT = 4; }
  else return;
  int l = idx & 63;
  int ct = (idx >> 6) % CT;
  int c = idx / (64 * CT);
  int q = l >> 4;
  int n = ct * 16 + (l & 15);
  int mask = (1 << mpsh) - 1;
  half8_t v;
#pragma unroll
  for (int j = 0; j < 8; ++j) {
    int r = c * 32 + q * 8 + j;
    int k = r >> mpsh, i = r & mask;
    float f = 0.f;
    if (i < mi) {
      if (k < 128) f = w2[(size_t)(k * mi + i) * mo + n];
      else if (k == 128) f = b2[(size_t)i * mo + n];
    }
    v[j] = (_Float16)f;
  }
  *(half8_t*)(op + (size_t)idx * 8) = v;
}

// ---------------- L0/L1 message kernel (R6 structure) + optional fused CSR-fill blocks ----------
// msgp layout: [e][split][MO] (interleaved). FILLB: blocks >= NBLK*NSPLIT do CSR fill instead.
template <int MIP, int MO, int NCC, int KCNT, int FILLB>
__global__ __launch_bounds__(256, 4) void msg9_kernel(
    const float* __restrict__ ea, const float* __restrict__ w1,
    const float* __restrict__ b1, const _Float16* __restrict__ xe,
    const int* __restrict__ src,
    const _Float16* __restrict__ w2h, _Float16* __restrict__ msgp,
    const int* __restrict__ dst, int* __restrict__ cursor, int* __restrict__ eids)
{
  if constexpr (FILLB) {
    if (blockIdx.x >= NBLK * NSPLIT) {
      int e = (blockIdx.x - NBLK * NSPLIT) * 256 + threadIdx.x;
      if (e < NE) { int p = atomicAdd(&cursor[dst[e]], 1); eids[p] = e; }
      return;
    }
  }
  constexpr int EPB = 128;                // edges per block
  constexpr int CT = MO / 16;
  constexpr int CHB = CT * 1024;          // BYTES per K32-chunk of W image
  constexpr int XV = (MIP == 64) ? 2 : 1;
  constexpr int KH = (KCNT + 1) >> 1;     // h k-values per thread-half

  __shared__ uint4 wsb[2][CHB / 16];
  __shared__ _Float16 h16[KCNT * EPB];    // transposed: h16[kl][edge]
  __shared__ float w1s[5 * 128 + 128];

  const int t = threadIdx.x;
  const int wave = t >> 6, lane = t & 63;
  const int l15 = lane & 15, q = lane >> 4;
  const int split = blockIdx.x / NBLK;
  const int e0 = (blockIdx.x % NBLK) * EPB;
  const int c0 = NCC * split;
  const int kg0 = KCNT * split;

  // ---- W prefetch: first two chunks into named registers ----
  const char* wgp = (const char*)w2h + (size_t)c0 * CHB;
  uint4 ra4, rb4; uint2 ra2, rb2;
  if constexpr (CT == 4) {
    ra4 = *(const uint4*)(wgp + t * 16);
    rb4 = *(const uint4*)(wgp + CHB + t * 16);
  } else {
    ra2 = *(const uint2*)(wgp + t * 8);
    rb2 = *(const uint2*)(wgp + CHB + t * 8);
  }

  // ---- x fragments direct from global (2 M-subtiles per wave) ----
  const int wbase = wave * 32;
  half8_t xf[2][XV];
#pragma unroll
  for (int s = 0; s < 2; ++s) {
    int eg = e0 + wbase + s * 16 + l15; if (eg >= NE) eg = NE - 1;
    const _Float16* xr = xe + (size_t)src[eg] * MIP;
    int i0 = (MIP == 16) ? (q & 1) * 8 : q * 8;
    xf[s][0] = *(const half8_t*)(xr + i0);
    if constexpr (MIP == 64)
      xf[s][XV - 1] = *(const half8_t*)(xr + 32 + q * 8);
  }

  // ---- edge attrs to regs (thread-half te owns edge e0+te); w1/b1 to LDS ----
  const int te = t & 127;
  float ear[5];
  {
    int eg = e0 + te; if (eg >= NE) eg = NE - 1;
#pragma unroll
    for (int j = 0; j < 5; ++j) ear[j] = ea[(size_t)eg * 5 + j];
  }
  for (int i = t; i < 768; i += 256) w1s[i] = (i < 640) ? w1[i] : b1[i - 640];
  __syncthreads();

  // ---- h phase: each edge's KCNT values split across thread halves ----
  {
    int kh = t >> 7;
    int klo = kh * KH;
    int khi = klo + KH; if (khi > KCNT) khi = KCNT;
    for (int kl = klo; kl < khi; ++kl) {
      int kg = kg0 + kl;
      float v;
      if (kg < 128) {
        v = w1s[640 + kg];
#pragma unroll
        for (int j = 0; j < 5; ++j) v = fmaf(ear[j], w1s[j * 128 + kg], v);
        v = fmaxf(v, 0.f);
      } else v = (kg == 128) ? 1.f : 0.f;
      h16[kl * EPB + te] = (_Float16)v;
    }
  }
  __syncthreads();

  // ---- K loop: 1 barrier/chunk, LDS double-buffer, 2-deep register prefetch ----
  floatx4 acc[2][CT];
#pragma unroll
  for (int s = 0; s < 2; ++s)
#pragma unroll
    for (int b = 0; b < CT; ++b) acc[s][b] = (floatx4){0.f, 0.f, 0.f, 0.f};

#pragma unroll 2
  for (int cc = 0; cc < NCC; ++cc) {
    const bool odd = (cc & 1) != 0;
    if constexpr (CT == 4) wsb[cc & 1][t] = odd ? rb4 : ra4;
    else ((uint2*)wsb[cc & 1])[t] = odd ? rb2 : ra2;
    if (cc + 2 < NCC) {
      const char* np = wgp + (size_t)(cc + 2) * CHB;
      if constexpr (CT == 4) {
        if (odd) rb4 = *(const uint4*)(np + t * 16); else ra4 = *(const uint4*)(np + t * 16);
      } else {
        if (odd) rb2 = *(const uint2*)(np + t * 8); else ra2 = *(const uint2*)(np + t * 8);
      }
    }
    __syncthreads();
    const _Float16* wb = (const _Float16*)wsb[cc & 1];
    half8_t bf[CT];
#pragma unroll
    for (int b = 0; b < CT; ++b)
      bf[b] = *(const half8_t*)(wb + (b * 64 + lane) * 8);
    int kl;
    if constexpr (MIP == 64) kl = cc >> 1;
    else if constexpr (MIP == 32) kl = cc;
    else kl = 2 * cc + (q >> 1);
#pragma unroll
    for (int s = 0; s < 2; ++s) {
      _Float16 hv = h16[kl * EPB + wbase + s * 16 + l15];
      half8_t af;
      if constexpr (MIP == 64) af = xf[s][cc & 1] * hv;
      else af = xf[s][0] * hv;
#pragma unroll
      for (int b = 0; b < CT; ++b)
        acc[s][b] = __builtin_amdgcn_mfma_f32_16x16x32_f16(af, bf[b], acc[s][b], 0, 0, 0);
    }
  }

  // ---- epilogue: interleaved partial stores msgp[e][split][MO], no atomics ----
#pragma unroll
  for (int s = 0; s < 2; ++s) {
    int rowb = wbase + s * 16 + q * 4;
#pragma unroll
    for (int b = 0; b < CT; ++b) {
      int n = b * 16 + l15;
#pragma unroll
      for (int r = 0; r < 4; ++r) {
        int row = rowb + r;
        int e = e0 + row;
        if (e < NE) msgp[((size_t)e * NSPLIT + split) * MO + n] = (_Float16)acc[s][b][r];
      }
    }
  }
}

// ---------------- L2 message kernel: msg9 structure with 2 chunks per barrier ----------------
// 4 NAMED uint4 prefetch regs (ternaries fold to cndmask, no scratch). 32 MFMA/wave/barrier.
template <int MIP, int NCC, int KCNT>
__global__ __launch_bounds__(256, 4) void msg9p_kernel(
    const float* __restrict__ ea, const float* __restrict__ w1,
    const float* __restrict__ b1, const _Float16* __restrict__ xe,
    const int* __restrict__ src,
    const _Float16* __restrict__ w2h, _Float16* __restrict__ msgp)
{
  constexpr int EPB = 128;
  constexpr int MO = 64;
  constexpr int CT = 4;
  constexpr int CHB = 4096;               // bytes per K32 chunk
  constexpr int XV = (MIP == 64) ? 2 : 1;
  constexpr int KH = (KCNT + 1) >> 1;
  static_assert((NCC & 1) == 0, "NCC must be even for paired chunks");

  __shared__ uint4 wsb[2][2][CHB / 16];   // [buffer][chunk-in-pair][256]
  __shared__ _Float16 h16[KCNT * EPB];    // transposed: h16[kl][edge]
  __shared__ float w1s[5 * 128 + 128];

  const int t = threadIdx.x;
  const int wave = t >> 6, lane = t & 63;
  const int l15 = lane & 15, q = lane >> 4;
  const int split = blockIdx.x / NBLK;
  const int e0 = (blockIdx.x % NBLK) * EPB;
  const int c0 = NCC * split;
  const int kg0 = KCNT * split;

  // ---- W prefetch: first four chunks into NAMED registers ----
  const char* wgp = (const char*)w2h + (size_t)c0 * CHB;
  uint4 pA0 = *(const uint4*)(wgp + 0 * CHB + t * 16);
  uint4 pA1 = *(const uint4*)(wgp + 1 * CHB + t * 16);
  uint4 pB0 = *(const uint4*)(wgp + 2 * CHB + t * 16);
  uint4 pB1 = *(const uint4*)(wgp + 3 * CHB + t * 16);

  // ---- x fragments direct from global (2 M-subtiles per wave) ----
  const int wbase = wave * 32;
  half8_t xf[2][XV];
#pragma unroll
  for (int s = 0; s < 2; ++s) {
    int eg = e0 + wbase + s * 16 + l15; if (eg >= NE) eg = NE - 1;
    const _Float16* xr = xe + (size_t)src[eg] * MIP;
    xf[s][0] = *(const half8_t*)(xr + q * 8);
    if constexpr (MIP == 64)
      xf[s][XV - 1] = *(const half8_t*)(xr + 32 + q * 8);
  }

  // ---- edge attrs to regs (thread-half te owns edge e0+te); w1/b1 to LDS ----
  const int te = t & 127;
  float ear[5];
  {
    int eg = e0 + te; if (eg >= NE) eg = NE - 1;
#pragma unroll
    for (int j = 0; j < 5; ++j) ear[j] = ea[(size_t)eg * 5 + j];
  }
  for (int i = t; i < 768; i += 256) w1s[i] = (i < 640) ? w1[i] : b1[i - 640];
  __syncthreads();

  // ---- h phase: each edge's KCNT values split across thread halves ----
  {
    int kh = t >> 7;
    int klo = kh * KH;
    int khi = klo + KH; if (khi > KCNT) khi = KCNT;
    for (int kl = klo; kl < khi; ++kl) {
      int kg = kg0 + kl;
      float v;
      if (kg < 128) {
        v = w1s[640 + kg];
#pragma unroll
        for (int j = 0; j < 5; ++j) v = fmaf(ear[j], w1s[j * 128 + kg], v);
        v = fmaxf(v, 0.f);
      } else v = (kg == 128) ? 1.f : 0.f;
      h16[kl * EPB + te] = (_Float16)v;
    }
  }
  __syncthreads();

  // ---- K loop: ONE barrier per 2-chunk pair, double-buffered pair slots ----
  floatx4 acc[2][CT];
#pragma unroll
  for (int s = 0; s < 2; ++s)
#pragma unroll
    for (int b = 0; b < CT; ++b) acc[s][b] = (floatx4){0.f, 0.f, 0.f, 0.f};

#pragma unroll 2
  for (int ci = 0; ci < NCC / 2; ++ci) {
    const bool odd = (ci & 1) != 0;
    wsb[ci & 1][0][t] = odd ? pB0 : pA0;
    wsb[ci & 1][1][t] = odd ? pB1 : pA1;
    if (2 * ci + 4 < NCC) {
      const char* np = wgp + (size_t)(2 * ci + 4) * CHB;
      if (odd) pB0 = *(const uint4*)(np + t * 16); else pA0 = *(const uint4*)(np + t * 16);
    }
    if (2 * ci + 5 < NCC) {
      const char* np = wgp + (size_t)(2 * ci + 5) * CHB;
      if (odd) pB1 = *(const uint4*)(np + t * 16); else pA1 = *(const uint4*)(np + t * 16);
    }
    __syncthreads();
#pragma unroll
    for (int u = 0; u < 2; ++u) {
      const int cc = 2 * ci + u;
      const _Float16* wbu = (const _Float16*)wsb[ci & 1][u];
      half8_t bf[CT];
#pragma unroll
      for (int b = 0; b < CT; ++b)
        bf[b] = *(const half8_t*)(wbu + (b * 64 + lane) * 8);
      int kl;
      if constexpr (MIP == 64) kl = cc >> 1;
      else kl = cc;
#pragma unroll
      for (int s = 0; s < 2; ++s) {
        _Float16 hv = h16[kl * EPB + wbase + s * 16 + l15];
        half8_t af;
        if constexpr (MIP == 64) af = xf[s][cc & 1] * hv;
        else af = xf[s][0] * hv;
#pragma unroll
        for (int b = 0; b < CT; ++b)
          acc[s][b] = __builtin_amdgcn_mfma_f32_16x16x32_f16(af, bf[b], acc[s][b], 0, 0, 0);
      }
    }
  }

  // ---- epilogue: interleaved partial stores msgp[e][split][64], no atomics ----
#pragma unroll
  for (int s = 0; s < 2; ++s) {
    int rowb = wbase + s * 16 + q * 4;
#pragma unroll
    for (int b = 0; b < CT; ++b) {
      int n = b * 16 + l15;
#pragma unroll
      for (int r = 0; r < 4; ++r) {
        int row = rowb + r;
        int e = e0 + row;
        if (e < NE) msgp[((size_t)e * NSPLIT + split) * MO + n] = (_Float16)acc[s][b][r];
      }
    }
  }
}

// ---- gather: per node, sum CSR-listed edge partials (+root-GEMM +bias), ELU unless FINAL ----
// msgp interleaved [e][split][MO]: one contiguous NSPLIT*MO block per edge.
template <int MIN_, int XST, int MO, int FINAL>
__global__ __launch_bounds__(256) void gather_kernel(
    const _Float16* __restrict__ e16in, const float* __restrict__ root,
    const float* __restrict__ bias, const int* __restrict__ row_ptr,
    const int* __restrict__ eids, const _Float16* __restrict__ msgp,
    _Float16* __restrict__ oute, float* __restrict__ outf)
{
  constexpr int NPB = 256 / MO;
  int n = blockIdx.x * NPB + threadIdx.x / MO;
  int o = threadIdx.x % MO;
  if (n >= NN) return;
  float a = bias[o];
#pragma unroll
  for (int i = 0; i < MIN_; ++i)
    a = fmaf((float)e16in[(size_t)n * XST + i], root[i * MO + o], a);
  int r0 = row_ptr[n], r1 = row_ptr[n + 1];
  for (int j = r0; j < r1; ++j) {
    int e = eids[j];
    const _Float16* ep = msgp + (size_t)e * NSPLIT * MO + o;
#pragma unroll
    for (int s = 0; s < NSPLIT; ++s)
      a += (float)ep[s * MO];
  }
  if constexpr (FINAL) {
    outf[(size_t)n * MO + o] = a;
  } else {
    float v = a > 0.f ? a : (expf(a) - 1.f);
    oute[(size_t)n * MO + o] = (_Float16)v;
  }
}

// ---- pooling (segment mean over sorted batch, fused ELU) + 3-layer FC head ----
__global__ __launch_bounds__(64) void pool_fc_kernel(
    const float* __restrict__ xn2, const int* __restrict__ batch,
    const float* __restrict__ f1w, const float* __restrict__ f1b,
    const float* __restrict__ f2w, const float* __restrict__ f2b,
    const float* __restrict__ f3w, const float* __restrict__ f3b,
    float* __restrict__ out)
{
  __shared__ float xg[64]; __shared__ float a1[32]; __shared__ float a2[16];
  int g = blockIdx.x, t = threadIdx.x;
  int lo = 0, hi = NN;
  while (lo < hi) { int m = (lo + hi) >> 1; if (batch[m] < g) lo = m + 1; else hi = m; }
  int start = lo; hi = NN;
  while (lo < hi) { int m = (lo + hi) >> 1; if (batch[m] <= g) lo = m + 1; else hi = m; }
  int end = lo;
  float acc = 0.f;
  for (int n = start; n < end; ++n) {
    float v = xn2[(size_t)n * 64 + t];
    acc += v > 0.f ? v : (expf(v) - 1.f);
  }
  float c = (end > start) ? (float)(end - start) : 1.f;
  xg[t] = acc / c;
  __syncthreads();
  if (t < 32) {
    float a = f1b[t];
    for (int i = 0; i < 64; ++i) a = fmaf(xg[i], f1w[i * 32 + t], a);
    a1[t] = a > 0.f ? a : (expf(a) - 1.f);
  }
  __syncthreads();
  if (t < 16) {
    float a = f2b[t];
    for (int i = 0; i < 32; ++i) a = fmaf(a1[i], f2w[i * 16 + t], a);
    a2[t] = a > 0.f ? a : (expf(a) - 1.f);
  }
  __syncthreads();
  if (t == 0) {
    float a = f3b[0];
    for (int i = 0; i < 16; ++i) a = fmaf(a2[i], f3w[i], a);
    out[g] = a;
  }
}

extern "C" void kernel_launch(void* const* d_in, const int* in_sizes, int n_in,
                              void* d_out, int out_size, void* d_ws, size_t ws_size,
                              hipStream_t stream)
{
  const float* x_in  = (const float*)d_in[0];
  const int*   ei    = (const int*)d_in[1];
  const float* ea    = (const float*)d_in[2];
  const int*   batch = (const int*)d_in[3];
  const float* W1[3] = {(const float*)d_in[4],  (const float*)d_in[10], (const float*)d_in[16]};
  const float* B1[3] = {(const float*)d_in[5],  (const float*)d_in[11], (const float*)d_in[17]};
  const float* W2[3] = {(const float*)d_in[6],  (const float*)d_in[12], (const float*)d_in[18]};
  const float* B2[3] = {(const float*)d_in[7],  (const float*)d_in[13], (const float*)d_in[19]};
  const float* RT[3] = {(const float*)d_in[8],  (const float*)d_in[14], (const float*)d_in[20]};
  const float* BS[3] = {(const float*)d_in[9],  (const float*)d_in[15], (const float*)d_in[21]};
  const float* f1w = (const float*)d_in[22]; const float* f1b = (const float*)d_in[23];
  const float* f2w = (const float*)d_in[24]; const float* f2b = (const float*)d_in[25];
  const float* f3w = (const float*)d_in[26]; const float* f3b = (const float*)d_in[27];

  char* ws = (char*)d_ws;
  size_t off = 0;
  auto alloc = [&](size_t bytes) { void* p = ws + off; off += (bytes + 255) & ~(size_t)255; return p; };
  float*    xn2   = (float*)alloc((size_t)NN * 64 * 4);
  _Float16* e16_0 = (_Float16*)alloc((size_t)NN * 16 * 2);
  _Float16* e16_1 = (_Float16*)alloc((size_t)NN * 32 * 2);
  _Float16* e16_2 = (_Float16*)alloc((size_t)NN * 64 * 2);
  _Float16* w2h0  = (_Float16*)alloc((size_t)68 * 2048);
  _Float16* w2h1  = (_Float16*)alloc((size_t)132 * 4096);
  _Float16* w2h2  = (_Float16*)alloc((size_t)264 * 4096);
  _Float16* msgp  = (_Float16*)alloc((size_t)NSPLIT * NE * 64 * 2);
  int*      row_ptr = (int*)alloc((size_t)(NN + 1) * 4);
  int*      cursor  = (int*)alloc((size_t)NN * 4);
  int*      eids    = (int*)alloc((size_t)NE * 4);

  const int* srcp = ei;
  const int* dstp = ei + NE;

  // dispatch 1: prep (x-pad + W2 images) || CSR deg+scan (block 0)
  prep_csr_kernel<<<422, 1024, 0, stream>>>(
      x_in, e16_0, W2[0], B2[0], w2h0, W2[1], B2[1], w2h1, W2[2], B2[2], w2h2,
      dstp, row_ptr, cursor);

  // dispatch 2: layer-0 msg || CSR fill (last 157 blocks)
  msg9_kernel<16, 32, 17, 34, 1><<<NBLK * NSPLIT + 157, 256, 0, stream>>>(
      ea, W1[0], B1[0], e16_0, srcp, w2h0, msgp, dstp, cursor, eids);
  gather_kernel<13, 16, 32, 0><<<(NN + 7) / 8, 256, 0, stream>>>(
      e16_0, RT[0], BS[0], row_ptr, eids, msgp, e16_1, xn2);

  // layer 1
  msg9_kernel<32, 64, 33, 33, 0><<<NBLK * NSPLIT, 256, 0, stream>>>(
      ea, W1[1], B1[1], e16_1, srcp, w2h1, msgp, nullptr, nullptr, nullptr);
  gather_kernel<32, 32, 64, 0><<<(NN + 3) / 4, 256, 0, stream>>>(
      e16_1, RT[1], BS[1], row_ptr, eids, msgp, e16_2, xn2);

  // layer 2
  msg9p_kernel<64, 66, 33><<<NBLK * NSPLIT, 256, 0, stream>>>(
      ea, W1[2], B1[2], e16_2, srcp, w2h2, msgp);
  gather_kernel<64, 64, 64, 1><<<(NN + 3) / 4, 256, 0, stream>>>(
      e16_2, RT[2], BS[2], row_ptr, eids, msgp, e16_2, xn2);

  pool_fc_kernel<<<NG, 64, 0, stream>>>(xn2, batch, f1w, f1b, f2w, f2b, f3w, f3b, (float*)d_out);
}

// Round 14
// 265.308 us; speedup vs baseline: 1.1731x; 1.0646x over previous
//
#include <hip/hip_runtime.h>
#include <stdint.h>
#include <math.h>

typedef _Float16 half8_t __attribute__((ext_vector_type(8)));
typedef float floatx4 __attribute__((ext_vector_type(4)));

#define NN 20000
#define NE 40000
#define NG 1000
#define NBLK 313      // ceil(NE/128)  -- 128 edges per block
#define NSPLIT 4

// ---------------- fused prep + CSR(deg+scan): one kernel, 1024 threads ----------------
// block 0           : degree histogram in LDS + parallel scan -> row_ptr, cursor
// blocks 1..313     : x -> e16 pad (NN*16 = 320000 elems)
// blocks 314..421   : w2 -> B-frag images (110080 half8 elems: L0 68, L1 132, L2 264 chunks)
__global__ __launch_bounds__(1024) void prep_csr_kernel(
    const float* __restrict__ x, _Float16* __restrict__ e16,
    const float* __restrict__ w2a, const float* __restrict__ b2a, _Float16* __restrict__ oa,
    const float* __restrict__ w2b, const float* __restrict__ b2b, _Float16* __restrict__ ob,
    const float* __restrict__ w2c, const float* __restrict__ b2c, _Float16* __restrict__ oc,
    const int* __restrict__ dst, int* __restrict__ row_ptr, int* __restrict__ cursor)
{
  __shared__ int sdeg[20480];            // 80 KB; used by block 0 only
  __shared__ int wsum[16];

  if (blockIdx.x == 0) {
    constexpr int CH = 20;               // 1024*20 = 20480 >= NN+1
    int t = threadIdx.x;
    int lane = t & 63, w = t >> 6;
    for (int i = t; i < 20480; i += 1024) sdeg[i] = 0;
    __syncthreads();
    for (int e = t; e < NE; e += 1024) atomicAdd(&sdeg[dst[e]], 1);
    __syncthreads();
    int base = t * CH;
    int local[CH];
#pragma unroll
    for (int i = 0; i < CH; ++i) local[i] = sdeg[base + i];
    int s = 0;
#pragma unroll
    for (int i = 0; i < CH; ++i) s += local[i];
    int sc = s;
#pragma unroll
    for (int d = 1; d < 64; d <<= 1) {
      int v = __shfl_up(sc, d, 64);
      if (lane >= d) sc += v;
    }
    if (lane == 63) wsum[w] = sc;
    __syncthreads();
    if (w == 0 && lane < 16) {
      int v = wsum[lane];
      int scc = v;
#pragma unroll
      for (int d = 1; d < 16; d <<= 1) {
        int u = __shfl_up(scc, d, 64);
        if (lane >= d) scc += u;
      }
      wsum[lane] = scc - v;              // exclusive wave prefix
    }
    __syncthreads();
    int run = wsum[w] + (sc - s);        // exclusive prefix for this thread
#pragma unroll
    for (int i = 0; i < CH; ++i) {
      int n = base + i;
      if (n < NN) { row_ptr[n] = run; cursor[n] = run; run += local[i]; }
      else if (n == NN) row_ptr[NN] = run;
    }
    return;
  }

  if (blockIdx.x <= 313) {
    int idx = (blockIdx.x - 1) * 1024 + threadIdx.x;   // over NN*16
    if (idx >= NN * 16) return;
    int n = idx >> 4, i = idx & 15;
    e16[idx] = (i < 13) ? (_Float16)x[(size_t)n * 13 + i] : (_Float16)0.f;
    return;
  }

  const int TOT0 = 68 * 2 * 64, TOT1 = 132 * 4 * 64, TOT2 = 264 * 4 * 64;
  int idx = (blockIdx.x - 314) * 1024 + threadIdx.x;
  const float *w2, *b2; _Float16* op; int mi, mo, mpsh, CT;
  if (idx < TOT0) { w2 = w2a; b2 = b2a; op = oa; mi = 13; mo = 32; mpsh = 4; CT = 2; }
  else if (idx < TOT0 + TOT1) { idx -= TOT0; w2 = w2b; b2 = b2b; op = ob; mi = 32; mo = 64; mpsh = 5; CT = 4; }
  else if (idx < TOT0 + TOT1 + TOT2) { idx -= TOT0 + TOT1; w2 = w2c; b2 = b2c; op = oc; mi = 64; mo = 64; mpsh = 6; CT = 4; }
  else return;
  int l = idx & 63;
  int ct = (idx >> 6) % CT;
  int c = idx / (64 * CT);
  int q = l >> 4;
  int n = ct * 16 + (l & 15);
  int mask = (1 << mpsh) - 1;
  half8_t v;
#pragma unroll
  for (int j = 0; j < 8; ++j) {
    int r = c * 32 + q * 8 + j;
    int k = r >> mpsh, i = r & mask;
    float f = 0.f;
    if (i < mi) {
      if (k < 128) f = w2[(size_t)(k * mi + i) * mo + n];
      else if (k == 128) f = b2[(size_t)i * mo + n];
    }
    v[j] = (_Float16)f;
  }
  *(half8_t*)(op + (size_t)idx * 8) = v;
}

// ---------------- L0/L1 message kernel (R6 structure) + optional fused CSR-fill blocks ----------
// msgp layout: [e][split][MO] (interleaved). FILLB: blocks >= NBLK*NSPLIT do CSR fill instead.
template <int MIP, int MO, int NCC, int KCNT, int FILLB>
__global__ __launch_bounds__(256, 4) void msg9_kernel(
    const float* __restrict__ ea, const float* __restrict__ w1,
    const float* __restrict__ b1, const _Float16* __restrict__ xe,
    const int* __restrict__ src,
    const _Float16* __restrict__ w2h, _Float16* __restrict__ msgp,
    const int* __restrict__ dst, int* __restrict__ cursor, int* __restrict__ eids)
{
  if constexpr (FILLB) {
    if (blockIdx.x >= NBLK * NSPLIT) {
      int e = (blockIdx.x - NBLK * NSPLIT) * 256 + threadIdx.x;
      if (e < NE) { int p = atomicAdd(&cursor[dst[e]], 1); eids[p] = e; }
      return;
    }
  }
  constexpr int EPB = 128;                // edges per block
  constexpr int CT = MO / 16;
  constexpr int CHB = CT * 1024;          // BYTES per K32-chunk of W image
  constexpr int XV = (MIP == 64) ? 2 : 1;
  constexpr int KH = (KCNT + 1) >> 1;     // h k-values per thread-half

  __shared__ uint4 wsb[2][CHB / 16];
  __shared__ _Float16 h16[KCNT * EPB];    // transposed: h16[kl][edge]
  __shared__ float w1s[5 * 128 + 128];

  const int t = threadIdx.x;
  const int wave = t >> 6, lane = t & 63;
  const int l15 = lane & 15, q = lane >> 4;
  const int split = blockIdx.x / NBLK;
  const int e0 = (blockIdx.x % NBLK) * EPB;
  const int c0 = NCC * split;
  const int kg0 = KCNT * split;

  // ---- W prefetch: first two chunks into named registers ----
  const char* wgp = (const char*)w2h + (size_t)c0 * CHB;
  uint4 ra4, rb4; uint2 ra2, rb2;
  if constexpr (CT == 4) {
    ra4 = *(const uint4*)(wgp + t * 16);
    rb4 = *(const uint4*)(wgp + CHB + t * 16);
  } else {
    ra2 = *(const uint2*)(wgp + t * 8);
    rb2 = *(const uint2*)(wgp + CHB + t * 8);
  }

  // ---- x fragments direct from global (2 M-subtiles per wave) ----
  const int wbase = wave * 32;
  half8_t xf[2][XV];
#pragma unroll
  for (int s = 0; s < 2; ++s) {
    int eg = e0 + wbase + s * 16 + l15; if (eg >= NE) eg = NE - 1;
    const _Float16* xr = xe + (size_t)src[eg] * MIP;
    int i0 = (MIP == 16) ? (q & 1) * 8 : q * 8;
    xf[s][0] = *(const half8_t*)(xr + i0);
    if constexpr (MIP == 64)
      xf[s][XV - 1] = *(const half8_t*)(xr + 32 + q * 8);
  }

  // ---- edge attrs to regs (thread-half te owns edge e0+te); w1/b1 to LDS ----
  const int te = t & 127;
  float ear[5];
  {
    int eg = e0 + te; if (eg >= NE) eg = NE - 1;
#pragma unroll
    for (int j = 0; j < 5; ++j) ear[j] = ea[(size_t)eg * 5 + j];
  }
  for (int i = t; i < 768; i += 256) w1s[i] = (i < 640) ? w1[i] : b1[i - 640];
  __syncthreads();

  // ---- h phase: each edge's KCNT values split across thread halves ----
  {
    int kh = t >> 7;
    int klo = kh * KH;
    int khi = klo + KH; if (khi > KCNT) khi = KCNT;
    for (int kl = klo; kl < khi; ++kl) {
      int kg = kg0 + kl;
      float v;
      if (kg < 128) {
        v = w1s[640 + kg];
#pragma unroll
        for (int j = 0; j < 5; ++j) v = fmaf(ear[j], w1s[j * 128 + kg], v);
        v = fmaxf(v, 0.f);
      } else v = (kg == 128) ? 1.f : 0.f;
      h16[kl * EPB + te] = (_Float16)v;
    }
  }
  __syncthreads();

  // ---- K loop: 1 barrier/chunk, LDS double-buffer, 2-deep register prefetch ----
  floatx4 acc[2][CT];
#pragma unroll
  for (int s = 0; s < 2; ++s)
#pragma unroll
    for (int b = 0; b < CT; ++b) acc[s][b] = (floatx4){0.f, 0.f, 0.f, 0.f};

#pragma unroll 2
  for (int cc = 0; cc < NCC; ++cc) {
    const bool odd = (cc & 1) != 0;
    if constexpr (CT == 4) wsb[cc & 1][t] = odd ? rb4 : ra4;
    else ((uint2*)wsb[cc & 1])[t] = odd ? rb2 : ra2;
    if (cc + 2 < NCC) {
      const char* np = wgp + (size_t)(cc + 2) * CHB;
      if constexpr (CT == 4) {
        if (odd) rb4 = *(const uint4*)(np + t * 16); else ra4 = *(const uint4*)(np + t * 16);
      } else {
        if (odd) rb2 = *(const uint2*)(np + t * 8); else ra2 = *(const uint2*)(np + t * 8);
      }
    }
    __syncthreads();
    const _Float16* wb = (const _Float16*)wsb[cc & 1];
    half8_t bf[CT];
#pragma unroll
    for (int b = 0; b < CT; ++b)
      bf[b] = *(const half8_t*)(wb + (b * 64 + lane) * 8);
    int kl;
    if constexpr (MIP == 64) kl = cc >> 1;
    else if constexpr (MIP == 32) kl = cc;
    else kl = 2 * cc + (q >> 1);
#pragma unroll
    for (int s = 0; s < 2; ++s) {
      _Float16 hv = h16[kl * EPB + wbase + s * 16 + l15];
      half8_t af;
      if constexpr (MIP == 64) af = xf[s][cc & 1] * hv;
      else af = xf[s][0] * hv;
#pragma unroll
      for (int b = 0; b < CT; ++b)
        acc[s][b] = __builtin_amdgcn_mfma_f32_16x16x32_f16(af, bf[b], acc[s][b], 0, 0, 0);
    }
  }

  // ---- epilogue: interleaved partial stores msgp[e][split][MO], no atomics ----
#pragma unroll
  for (int s = 0; s < 2; ++s) {
    int rowb = wbase + s * 16 + q * 4;
#pragma unroll
    for (int b = 0; b < CT; ++b) {
      int n = b * 16 + l15;
#pragma unroll
      for (int r = 0; r < 4; ++r) {
        int row = rowb + r;
        int e = e0 + row;
        if (e < NE) msgp[((size_t)e * NSPLIT + split) * MO + n] = (_Float16)acc[s][b][r];
      }
    }
  }
}

// ---------------- L2 message kernel: msg9 structure with 2 chunks per barrier ----------------
// 4 NAMED uint4 prefetch regs (ternaries fold to cndmask, no scratch). 32 MFMA/wave/barrier.
template <int MIP, int NCC, int KCNT>
__global__ __launch_bounds__(256, 4) void msg9p_kernel(
    const float* __restrict__ ea, const float* __restrict__ w1,
    const float* __restrict__ b1, const _Float16* __restrict__ xe,
    const int* __restrict__ src,
    const _Float16* __restrict__ w2h, _Float16* __restrict__ msgp)
{
  constexpr int EPB = 128;
  constexpr int MO = 64;
  constexpr int CT = 4;
  constexpr int CHB = 4096;               // bytes per K32 chunk
  constexpr int XV = (MIP == 64) ? 2 : 1;
  constexpr int KH = (KCNT + 1) >> 1;
  static_assert((NCC & 1) == 0, "NCC must be even for paired chunks");

  __shared__ uint4 wsb[2][2][CHB / 16];   // [buffer][chunk-in-pair][256]
  __shared__ _Float16 h16[KCNT * EPB];    // transposed: h16[kl][edge]
  __shared__ float w1s[5 * 128 + 128];

  const int t = threadIdx.x;
  const int wave = t >> 6, lane = t & 63;
  const int l15 = lane & 15, q = lane >> 4;
  const int split = blockIdx.x / NBLK;
  const int e0 = (blockIdx.x % NBLK) * EPB;
  const int c0 = NCC * split;
  const int kg0 = KCNT * split;

  // ---- W prefetch: first four chunks into NAMED registers ----
  const char* wgp = (const char*)w2h + (size_t)c0 * CHB;
  uint4 pA0 = *(const uint4*)(wgp + 0 * CHB + t * 16);
  uint4 pA1 = *(const uint4*)(wgp + 1 * CHB + t * 16);
  uint4 pB0 = *(const uint4*)(wgp + 2 * CHB + t * 16);
  uint4 pB1 = *(const uint4*)(wgp + 3 * CHB + t * 16);

  // ---- x fragments direct from global (2 M-subtiles per wave) ----
  const int wbase = wave * 32;
  half8_t xf[2][XV];
#pragma unroll
  for (int s = 0; s < 2; ++s) {
    int eg = e0 + wbase + s * 16 + l15; if (eg >= NE) eg = NE - 1;
    const _Float16* xr = xe + (size_t)src[eg] * MIP;
    xf[s][0] = *(const half8_t*)(xr + q * 8);
    if constexpr (MIP == 64)
      xf[s][XV - 1] = *(const half8_t*)(xr + 32 + q * 8);
  }

  // ---- edge attrs to regs (thread-half te owns edge e0+te); w1/b1 to LDS ----
  const int te = t & 127;
  float ear[5];
  {
    int eg = e0 + te; if (eg >= NE) eg = NE - 1;
#pragma unroll
    for (int j = 0; j < 5; ++j) ear[j] = ea[(size_t)eg * 5 + j];
  }
  for (int i = t; i < 768; i += 256) w1s[i] = (i < 640) ? w1[i] : b1[i - 640];
  __syncthreads();

  // ---- h phase: each edge's KCNT values split across thread halves ----
  {
    int kh = t >> 7;
    int klo = kh * KH;
    int khi = klo + KH; if (khi > KCNT) khi = KCNT;
    for (int kl = klo; kl < khi; ++kl) {
      int kg = kg0 + kl;
      float v;
      if (kg < 128) {
        v = w1s[640 + kg];
#pragma unroll
        for (int j = 0; j < 5; ++j) v = fmaf(ear[j], w1s[j * 128 + kg], v);
        v = fmaxf(v, 0.f);
      } else v = (kg == 128) ? 1.f : 0.f;
      h16[kl * EPB + te] = (_Float16)v;
    }
  }
  __syncthreads();

  // ---- K loop: ONE barrier per 2-chunk pair, double-buffered pair slots ----
  floatx4 acc[2][CT];
#pragma unroll
  for (int s = 0; s < 2; ++s)
#pragma unroll
    for (int b = 0; b < CT; ++b) acc[s][b] = (floatx4){0.f, 0.f, 0.f, 0.f};

#pragma unroll 2
  for (int ci = 0; ci < NCC / 2; ++ci) {
    const bool odd = (ci & 1) != 0;
    wsb[ci & 1][0][t] = odd ? pB0 : pA0;
    wsb[ci & 1][1][t] = odd ? pB1 : pA1;
    if (2 * ci + 4 < NCC) {
      const char* np = wgp + (size_t)(2 * ci + 4) * CHB;
      if (odd) pB0 = *(const uint4*)(np + t * 16); else pA0 = *(const uint4*)(np + t * 16);
    }
    if (2 * ci + 5 < NCC) {
      const char* np = wgp + (size_t)(2 * ci + 5) * CHB;
      if (odd) pB1 = *(const uint4*)(np + t * 16); else pA1 = *(const uint4*)(np + t * 16);
    }
    __syncthreads();
#pragma unroll
    for (int u = 0; u < 2; ++u) {
      const int cc = 2 * ci + u;
      const _Float16* wbu = (const _Float16*)wsb[ci & 1][u];
      half8_t bf[CT];
#pragma unroll
      for (int b = 0; b < CT; ++b)
        bf[b] = *(const half8_t*)(wbu + (b * 64 + lane) * 8);
      int kl;
      if constexpr (MIP == 64) kl = cc >> 1;
      else kl = cc;
#pragma unroll
      for (int s = 0; s < 2; ++s) {
        _Float16 hv = h16[kl * EPB + wbase + s * 16 + l15];
        half8_t af;
        if constexpr (MIP == 64) af = xf[s][cc & 1] * hv;
        else af = xf[s][0] * hv;
#pragma unroll
        for (int b = 0; b < CT; ++b)
          acc[s][b] = __builtin_amdgcn_mfma_f32_16x16x32_f16(af, bf[b], acc[s][b], 0, 0, 0);
      }
    }
  }

  // ---- epilogue: interleaved partial stores msgp[e][split][64], no atomics ----
#pragma unroll
  for (int s = 0; s < 2; ++s) {
    int rowb = wbase + s * 16 + q * 4;
#pragma unroll
    for (int b = 0; b < CT; ++b) {
      int n = b * 16 + l15;
#pragma unroll
      for (int r = 0; r < 4; ++r) {
        int row = rowb + r;
        int e = e0 + row;
        if (e < NE) msgp[((size_t)e * NSPLIT + split) * MO + n] = (_Float16)acc[s][b][r];
      }
    }
  }
}

// ---- gather: per node, sum CSR-listed edge partials (+root-GEMM +bias), ELU unless FINAL ----
// msgp interleaved [e][split][MO]; CSR loop 2-edge-unrolled into independent chains.
template <int MIN_, int XST, int MO, int FINAL>
__global__ __launch_bounds__(256) void gather_kernel(
    const _Float16* __restrict__ e16in, const float* __restrict__ root,
    const float* __restrict__ bias, const int* __restrict__ row_ptr,
    const int* __restrict__ eids, const _Float16* __restrict__ msgp,
    _Float16* __restrict__ oute, float* __restrict__ outf)
{
  constexpr int NPB = 256 / MO;
  int n = blockIdx.x * NPB + threadIdx.x / MO;
  int o = threadIdx.x % MO;
  if (n >= NN) return;
  float a = bias[o];
#pragma unroll
  for (int i = 0; i < MIN_; ++i)
    a = fmaf((float)e16in[(size_t)n * XST + i], root[i * MO + o], a);
  int r0 = row_ptr[n], r1 = row_ptr[n + 1];
  float a2 = 0.f;
  int j = r0;
  for (; j + 1 < r1; j += 2) {
    int e1 = eids[j], e2 = eids[j + 1];
    const _Float16* p1 = msgp + (size_t)e1 * NSPLIT * MO + o;
    const _Float16* p2 = msgp + (size_t)e2 * NSPLIT * MO + o;
#pragma unroll
    for (int s = 0; s < NSPLIT; ++s) {
      a  += (float)p1[s * MO];
      a2 += (float)p2[s * MO];
    }
  }
  if (j < r1) {
    int e = eids[j];
    const _Float16* ep = msgp + (size_t)e * NSPLIT * MO + o;
#pragma unroll
    for (int s = 0; s < NSPLIT; ++s)
      a += (float)ep[s * MO];
  }
  a += a2;
  if constexpr (FINAL) {
    outf[(size_t)n * MO + o] = a;
  } else {
    float v = a > 0.f ? a : (expf(a) - 1.f);
    oute[(size_t)n * MO + o] = (_Float16)v;
  }
}

// ---- pooling + FC head: 256 threads/graph, 4 waves split the node range (serial depth /4) ----
__global__ __launch_bounds__(256) void pool_fc_kernel(
    const float* __restrict__ xn2, const int* __restrict__ batch,
    const float* __restrict__ f1w, const float* __restrict__ f1b,
    const float* __restrict__ f2w, const float* __restrict__ f2b,
    const float* __restrict__ f3w, const float* __restrict__ f3b,
    float* __restrict__ out)
{
  __shared__ float xg4[4][64];
  __shared__ float xg[64]; __shared__ float a1[32]; __shared__ float a2[16];
  int g = blockIdx.x, t = threadIdx.x;
  int ch = t & 63, seg = t >> 6;
  int lo = 0, hi = NN;
  while (lo < hi) { int m = (lo + hi) >> 1; if (batch[m] < g) lo = m + 1; else hi = m; }
  int start = lo; hi = NN;
  while (lo < hi) { int m = (lo + hi) >> 1; if (batch[m] <= g) lo = m + 1; else hi = m; }
  int end = lo;
  float acc = 0.f;
  for (int n = start + seg; n < end; n += 4) {
    float v = xn2[(size_t)n * 64 + ch];
    acc += v > 0.f ? v : (expf(v) - 1.f);
  }
  xg4[seg][ch] = acc;
  __syncthreads();
  if (t < 64) {
    float c = (end > start) ? (float)(end - start) : 1.f;
    xg[t] = (xg4[0][t] + xg4[1][t] + xg4[2][t] + xg4[3][t]) / c;
  }
  __syncthreads();
  if (t < 32) {
    float a = f1b[t];
    for (int i = 0; i < 64; ++i) a = fmaf(xg[i], f1w[i * 32 + t], a);
    a1[t] = a > 0.f ? a : (expf(a) - 1.f);
  }
  __syncthreads();
  if (t < 16) {
    float a = f2b[t];
    for (int i = 0; i < 32; ++i) a = fmaf(a1[i], f2w[i * 16 + t], a);
    a2[t] = a > 0.f ? a : (expf(a) - 1.f);
  }
  __syncthreads();
  if (t == 0) {
    float a = f3b[0];
    for (int i = 0; i < 16; ++i) a = fmaf(a2[i], f3w[i], a);
    out[g] = a;
  }
}

extern "C" void kernel_launch(void* const* d_in, const int* in_sizes, int n_in,
                              void* d_out, int out_size, void* d_ws, size_t ws_size,
                              hipStream_t stream)
{
  const float* x_in  = (const float*)d_in[0];
  const int*   ei    = (const int*)d_in[1];
  const float* ea    = (const float*)d_in[2];
  const int*   batch = (const int*)d_in[3];
  const float* W1[3] = {(const float*)d_in[4],  (const float*)d_in[10], (const float*)d_in[16]};
  const float* B1[3] = {(const float*)d_in[5],  (const float*)d_in[11], (const float*)d_in[17]};
  const float* W2[3] = {(const float*)d_in[6],  (const float*)d_in[12], (const float*)d_in[18]};
  const float* B2[3] = {(const float*)d_in[7],  (const float*)d_in[13], (const float*)d_in[19]};
  const float* RT[3] = {(const float*)d_in[8],  (const float*)d_in[14], (const float*)d_in[20]};
  const float* BS[3] = {(const float*)d_in[9],  (const float*)d_in[15], (const float*)d_in[21]};
  const float* f1w = (const float*)d_in[22]; const float* f1b = (const float*)d_in[23];
  const float* f2w = (const float*)d_in[24]; const float* f2b = (const float*)d_in[25];
  const float* f3w = (const float*)d_in[26]; const float* f3b = (const float*)d_in[27];

  char* ws = (char*)d_ws;
  size_t off = 0;
  auto alloc = [&](size_t bytes) { void* p = ws + off; off += (bytes + 255) & ~(size_t)255; return p; };
  float*    xn2   = (float*)alloc((size_t)NN * 64 * 4);
  _Float16* e16_0 = (_Float16*)alloc((size_t)NN * 16 * 2);
  _Float16* e16_1 = (_Float16*)alloc((size_t)NN * 32 * 2);
  _Float16* e16_2 = (_Float16*)alloc((size_t)NN * 64 * 2);
  _Float16* w2h0  = (_Float16*)alloc((size_t)68 * 2048);
  _Float16* w2h1  = (_Float16*)alloc((size_t)132 * 4096);
  _Float16* w2h2  = (_Float16*)alloc((size_t)264 * 4096);
  _Float16* msgp  = (_Float16*)alloc((size_t)NSPLIT * NE * 64 * 2);
  int*      row_ptr = (int*)alloc((size_t)(NN + 1) * 4);
  int*      cursor  = (int*)alloc((size_t)NN * 4);
  int*      eids    = (int*)alloc((size_t)NE * 4);

  const int* srcp = ei;
  const int* dstp = ei + NE;

  // dispatch 1: prep (x-pad + W2 images) || CSR deg+scan (block 0)
  prep_csr_kernel<<<422, 1024, 0, stream>>>(
      x_in, e16_0, W2[0], B2[0], w2h0, W2[1], B2[1], w2h1, W2[2], B2[2], w2h2,
      dstp, row_ptr, cursor);

  // dispatch 2: layer-0 msg || CSR fill (last 157 blocks)
  msg9_kernel<16, 32, 17, 34, 1><<<NBLK * NSPLIT + 157, 256, 0, stream>>>(
      ea, W1[0], B1[0], e16_0, srcp, w2h0, msgp, dstp, cursor, eids);
  gather_kernel<13, 16, 32, 0><<<(NN + 7) / 8, 256, 0, stream>>>(
      e16_0, RT[0], BS[0], row_ptr, eids, msgp, e16_1, xn2);

  // layer 1
  msg9_kernel<32, 64, 33, 33, 0><<<NBLK * NSPLIT, 256, 0, stream>>>(
      ea, W1[1], B1[1], e16_1, srcp, w2h1, msgp, nullptr, nullptr, nullptr);
  gather_kernel<32, 32, 64, 0><<<(NN + 3) / 4, 256, 0, stream>>>(
      e16_1, RT[1], BS[1], row_ptr, eids, msgp, e16_2, xn2);

  // layer 2
  msg9p_kernel<64, 66, 33><<<NBLK * NSPLIT, 256, 0, stream>>>(
      ea, W1[2], B1[2], e16_2, srcp, w2h2, msgp);
  gather_kernel<64, 64, 64, 1><<<(NN + 3) / 4, 256, 0, stream>>>(
      e16_2, RT[2], BS[2], row_ptr, eids, msgp, e16_2, xn2);

  pool_fc_kernel<<<NG, 256, 0, stream>>>(xn2, batch, f1w, f1b, f2w, f2b, f3w, f3b, (float*)d_out);
}